// Round 6
// baseline (208.897 us; speedup 1.0000x reference)
//
#include <hip/hip_runtime.h>
#include <hip/hip_bf16.h>
#include <math.h>

namespace {
constexpr int Bb  = 8;
constexpr int Nn  = 2048;
constexpr int DIN_ = 256;
constexpr int DM_  = 256;
constexpr int NH_  = 4;
constexpr int DK_  = 64;
constexpr int BH_  = Bb * NH_;
constexpr float SCALE = 0.125f;   // 1/sqrt(64)
}

typedef __attribute__((ext_vector_type(8))) _Float16 half8;
typedef __attribute__((ext_vector_type(2))) __fp16 fp16x2;
typedef __attribute__((ext_vector_type(4))) float f32x4;

static __device__ __forceinline__ unsigned pkrtz_u32(float a, float b) {
    union { fp16x2 h; unsigned u; } u;
    u.h = __builtin_amdgcn_cvt_pkrtz(a, b);
    return u.u;
}

static __device__ __forceinline__ half8 h8_from_u32x4(unsigned w0, unsigned w1,
                                                      unsigned w2, unsigned w3) {
    union { unsigned u[4]; half8 h; } u;
    u.u[0] = w0; u.u[1] = w1; u.u[2] = w2; u.u[3] = w3;
    return u.h;
}

// ---------------------------------------------------------------------------
// Kernel 1 (fused prep): blocks 0-7 bounds, 8-2055 convert_x, 2056-2311 convert_w
// ---------------------------------------------------------------------------
__global__ __launch_bounds__(256) void prep_kernel(
    const int* __restrict__ mask, int* __restrict__ bounds,
    const float* __restrict__ x, _Float16* __restrict__ xh,
    const float* __restrict__ W0, const float* __restrict__ W1,
    const float* __restrict__ W2, const float* __restrict__ W3,
    _Float16* __restrict__ T0, _Float16* __restrict__ T1,
    _Float16* __restrict__ T2, _Float16* __restrict__ T3)
{
    const int bid = blockIdx.x;
    const int tid = threadIdx.x;
    if (bid < 8) {
        // ---- bounds ----
        const int b = bid;
        __shared__ int smin[256], smax[256];
        int lmin = Nn, lmax = -1;
        for (int i = tid; i < Nn; i += 256) {
            if (mask[b * Nn + i]) {
                if (i < lmin) lmin = i;
                if (i > lmax) lmax = i;
            }
        }
        smin[tid] = lmin; smax[tid] = lmax;
        __syncthreads();
        for (int s = 128; s > 0; s >>= 1) {
            if (tid < s) {
                smin[tid] = min(smin[tid], smin[tid + s]);
                smax[tid] = max(smax[tid], smax[tid + s]);
            }
            __syncthreads();
        }
        if (tid == 0) { bounds[b * 2] = smin[0]; bounds[b * 2 + 1] = smax[0]; }
    } else if (bid < 8 + 2048) {
        // ---- convert_x ----
        const size_t i = ((size_t)(bid - 8) * 256 + tid) * 8;
        float4 v0 = *(const float4*)&x[i];
        float4 v1 = *(const float4*)&x[i + 4];
        _Float16 h[8];
        h[0]=(_Float16)v0.x; h[1]=(_Float16)v0.y; h[2]=(_Float16)v0.z; h[3]=(_Float16)v0.w;
        h[4]=(_Float16)v1.x; h[5]=(_Float16)v1.y; h[6]=(_Float16)v1.z; h[7]=(_Float16)v1.w;
        *(uint4*)&xh[i] = *(const uint4*)h;
    } else {
        // ---- convert_w (transpose to [N][K] fp16) ----
        const int lin = bid - 2056;          // 0..255
        const int wsel = lin >> 6;           // 64 blocks per weight
        const float* W; _Float16* T;
        switch (wsel) {
            case 0: W = W0; T = T0; break;
            case 1: W = W1; T = T1; break;
            case 2: W = W2; T = T2; break;
            default: W = W3; T = T3; break;
        }
        const int idx = (lin & 63) * 256 + tid;   // [0, 16384)
        const int n = idx & 255;
        const int k0 = (idx >> 8) << 2;
        _Float16 h4[4];
        #pragma unroll
        for (int j = 0; j < 4; ++j) h4[j] = (_Float16)W[(size_t)(k0 + j) * 256 + n];
        *(uint2*)&T[(size_t)n * 256 + k0] = *(const uint2*)h4;
    }
}

// ---------------------------------------------------------------------------
// Kernel 2: QKV projection via fp16 MFMA.  (unchanged from R5, proven)
// ---------------------------------------------------------------------------
__global__ __launch_bounds__(256) void qkv_mfma(
    const _Float16* __restrict__ xh,
    const _Float16* __restrict__ Wtq, const float* __restrict__ bq,
    const _Float16* __restrict__ Wtk, const float* __restrict__ bk,
    const _Float16* __restrict__ Wtv, const float* __restrict__ bv,
    _Float16* __restrict__ Qh, _Float16* __restrict__ Kh, _Float16* __restrict__ Vt)
{
    const int z = blockIdx.z;
    const _Float16* Wt; const float* bias;
    if (z == 0)      { Wt = Wtq; bias = bq; }
    else if (z == 1) { Wt = Wtk; bias = bk; }
    else             { Wt = Wtv; bias = bv; }

    const int m0 = blockIdx.x * 128;
    const int n0 = blockIdx.y * 64;
    const int tid = threadIdx.x;
    const int w = tid >> 6, lane = tid & 63;
    const int a = lane & 15, g = lane >> 4;
    const int mb = m0 + 32 * w;

    f32x4 d0[4] = {{0,0,0,0},{0,0,0,0},{0,0,0,0},{0,0,0,0}};
    f32x4 d1[4] = {{0,0,0,0},{0,0,0,0},{0,0,0,0},{0,0,0,0}};

    const _Float16* A0 = xh + (size_t)(mb + a) * 256 + 8 * g;
    const _Float16* A1 = xh + (size_t)(mb + 16 + a) * 256 + 8 * g;
    const _Float16* Wr0 = Wt + (size_t)(n0 +  0 + a) * 256 + 8 * g;
    const _Float16* Wr1 = Wt + (size_t)(n0 + 16 + a) * 256 + 8 * g;
    const _Float16* Wr2 = Wt + (size_t)(n0 + 32 + a) * 256 + 8 * g;
    const _Float16* Wr3 = Wt + (size_t)(n0 + 48 + a) * 256 + 8 * g;

    #pragma unroll
    for (int kc = 0; kc < 8; ++kc) {
        const half8 af0 = *(const half8*)(A0 + 32 * kc);
        const half8 af1 = *(const half8*)(A1 + 32 * kc);
        const half8 b0 = *(const half8*)(Wr0 + 32 * kc);
        const half8 b1 = *(const half8*)(Wr1 + 32 * kc);
        const half8 b2 = *(const half8*)(Wr2 + 32 * kc);
        const half8 b3 = *(const half8*)(Wr3 + 32 * kc);
        d0[0] = __builtin_amdgcn_mfma_f32_16x16x32_f16(af0, b0, d0[0], 0,0,0);
        d1[0] = __builtin_amdgcn_mfma_f32_16x16x32_f16(af1, b0, d1[0], 0,0,0);
        d0[1] = __builtin_amdgcn_mfma_f32_16x16x32_f16(af0, b1, d0[1], 0,0,0);
        d1[1] = __builtin_amdgcn_mfma_f32_16x16x32_f16(af1, b1, d1[1], 0,0,0);
        d0[2] = __builtin_amdgcn_mfma_f32_16x16x32_f16(af0, b2, d0[2], 0,0,0);
        d1[2] = __builtin_amdgcn_mfma_f32_16x16x32_f16(af1, b2, d1[2], 0,0,0);
        d0[3] = __builtin_amdgcn_mfma_f32_16x16x32_f16(af0, b3, d0[3], 0,0,0);
        d1[3] = __builtin_amdgcn_mfma_f32_16x16x32_f16(af1, b3, d1[3], 0,0,0);
    }

    #pragma unroll
    for (int t = 0; t < 2; ++t) {
        const int mrow = mb + 16 * t + 4 * g;     // +reg
        #pragma unroll
        for (int nf = 0; nf < 4; ++nf) {
            const f32x4 dv = t == 0 ? d0[nf] : d1[nf];
            const int n = n0 + 16 * nf + a;
            const float bs = bias[n];
            const int bh = (mrow >> 11) * NH_ + (n >> 6);
            const int dk = n & 63;
            if (z < 2) {
                _Float16* out = z ? Kh : Qh;
                #pragma unroll
                for (int r = 0; r < 4; ++r) {
                    const int tok = (mrow + r) & 2047;
                    out[((size_t)bh * Nn + tok) * DK_ + dk] = (_Float16)(dv[r] + bs);
                }
            } else {
                const int tok = mrow & 2047;
                uint2 pk;
                pk.x = pkrtz_u32(dv[0] + bs, dv[1] + bs);
                pk.y = pkrtz_u32(dv[2] + bs, dv[3] + bs);
                *(uint2*)&Vt[((size_t)bh * DK_ + dk) * Nn + tok] = pk;
            }
        }
    }
}

// ---------------------------------------------------------------------------
// Kernel 3: column mean of V per (bh)  (unchanged)
// ---------------------------------------------------------------------------
__global__ __launch_bounds__(256) void colmean_kernel(const _Float16* __restrict__ Vt,
                                                      float* __restrict__ cm) {
    const int bh = blockIdx.x;
    const int t = threadIdx.x;
    const int d = t >> 2, part = t & 3;
    const _Float16* src = Vt + ((size_t)bh * DK_ + d) * Nn + part * 512;
    float s = 0.f;
    for (int i = 0; i < 512; i += 8) {
        half8 v = *(const half8*)(src + i);
        #pragma unroll
        for (int j = 0; j < 8; ++j) s += (float)v[j];
    }
    __shared__ float red[64][4];
    red[d][part] = s;
    __syncthreads();
    if (part == 0)
        cm[bh * DK_ + d] = (red[d][0] + red[d][1] + red[d][2] + red[d][3]) * (1.0f / 2048.0f);
}

// ---------------------------------------------------------------------------
// Kernel 4: flash attention, fp16 MFMA, span-restricted, DOUBLE-BUFFERED
// staging with counted vmcnt (stage t+1 overlaps compute t), XCD-swizzled
// grid (each XCD owns 4 bh -> 2MB K/V L2-resident).
// grid = 1024 1-D blocks: xcd=bid&7, rest=bid>>3, qb=rest&31, bh=(xcd<<2)|(rest>>5)
// ---------------------------------------------------------------------------
__global__ __launch_bounds__(256) void flash_mfma(
    const _Float16* __restrict__ Q, const _Float16* __restrict__ K,
    const _Float16* __restrict__ Vt, const int* __restrict__ bounds,
    const float* __restrict__ cm, _Float16* __restrict__ att)
{
    const int bid = blockIdx.x;
    const int xcd = bid & 7;
    const int rest = bid >> 3;
    const int qb  = rest & 31;
    const int bh  = (xcd << 2) | (rest >> 5);
    const int b  = bh >> 2, h = bh & 3;
    const int q0 = qb * 64;
    const int tid  = threadIdx.x;
    const int w    = tid >> 6;
    const int lane = tid & 63;
    const int a = lane & 15, g = lane >> 4;
    const int start = bounds[2 * b], endv = bounds[2 * b + 1];

    __shared__ __align__(16) _Float16 kfr[2][8][512];   // 16KB (2 buffers)
    __shared__ __align__(16) _Float16 vfr[2][8][512];   // 16KB

    const float* cmb = cm + bh * DK_;
    _Float16* attb = att + ((size_t)b * Nn) * DM_ + h * DK_;

    // fully-invalid block: uniform softmax over ALL columns == colmean
    if (q0 + 63 < start || q0 >= endv) {
        #pragma unroll
        for (int td = 0; td < 4; ++td) {
            const _Float16 cmv = (_Float16)cmb[16 * td + a];
            #pragma unroll
            for (int r = 0; r < 4; ++r) {
                const int qr = q0 + 16 * w + 4 * g + r;
                attb[(size_t)qr * DM_ + 16 * td + a] = cmv;
            }
        }
        return;
    }

    const _Float16* Qb = Q  + (size_t)bh * Nn * DK_;
    const _Float16* Kb = K  + (size_t)bh * Nn * DK_;
    const _Float16* Vb = Vt + (size_t)bh * DK_ * Nn;

    const int qrow = q0 + 16 * w + a;
    const half8 qf0 = *(const half8*)&Qb[(size_t)qrow * DK_ + 8 * g];
    const half8 qf1 = *(const half8*)&Qb[(size_t)qrow * DK_ + 32 + 8 * g];

    float l_i = 0.0f;
    f32x4 o0 = {0.f,0.f,0.f,0.f}, o1 = {0.f,0.f,0.f,0.f};
    f32x4 o2 = {0.f,0.f,0.f,0.f}, o3 = {0.f,0.f,0.f,0.f};

    // wave w stages frags 2w, 2w+1 (K and V) = 4 global_load_lds per wave
#define STAGE(cbuf, kt_) do {                                                        \
        _Pragma("unroll")                                                            \
        for (int ff = 0; ff < 2; ++ff) {                                             \
            const int f  = 2 * w + ff;                                               \
            const int tt = f >> 1, cc = f & 1;                                       \
            const _Float16* ks = &Kb[(size_t)((kt_) + 16 * tt + a) * DK_ + 32 * cc + 8 * g]; \
            __builtin_amdgcn_global_load_lds(                                        \
                (const __attribute__((address_space(1))) void*)ks,                   \
                (__attribute__((address_space(3))) void*)&kfr[cbuf][f][0], 16, 0, 0);\
            const _Float16* vs = &Vb[(size_t)(16 * tt + a) * Nn + (kt_) + 32 * cc + 8 * g]; \
            __builtin_amdgcn_global_load_lds(                                        \
                (const __attribute__((address_space(1))) void*)vs,                   \
                (__attribute__((address_space(3))) void*)&vfr[cbuf][f][0], 16, 0, 0);\
        }                                                                            \
    } while (0)

    const int lo = (start >> 6) * 64;
    int c = 0;
    STAGE(0, lo);

    for (int kt = lo; kt < endv; kt += 64) {
        const int nxt = kt + 64;
        if (nxt < endv) {
            STAGE(c ^ 1, nxt);
            asm volatile("s_waitcnt vmcnt(4)" ::: "memory");  // this buf's loads done
        } else {
            asm volatile("s_waitcnt vmcnt(0)" ::: "memory");
        }
        __builtin_amdgcn_s_barrier();   // all waves' staging of buf c complete

        const _Float16* kf = &kfr[c][0][0];
        const _Float16* vf = &vfr[c][0][0];

        // ---- S^T = K_tile · Q^T : D[kv=16t+4g+r][q=a] ----
        f32x4 st0 = {0.f,0.f,0.f,0.f}, st1 = {0.f,0.f,0.f,0.f};
        f32x4 st2 = {0.f,0.f,0.f,0.f}, st3 = {0.f,0.f,0.f,0.f};
        st0 = __builtin_amdgcn_mfma_f32_16x16x32_f16(*(const half8*)&kf[0*512 + lane*8], qf0, st0, 0,0,0);
        st0 = __builtin_amdgcn_mfma_f32_16x16x32_f16(*(const half8*)&kf[1*512 + lane*8], qf1, st0, 0,0,0);
        st1 = __builtin_amdgcn_mfma_f32_16x16x32_f16(*(const half8*)&kf[2*512 + lane*8], qf0, st1, 0,0,0);
        st1 = __builtin_amdgcn_mfma_f32_16x16x32_f16(*(const half8*)&kf[3*512 + lane*8], qf1, st1, 0,0,0);
        st2 = __builtin_amdgcn_mfma_f32_16x16x32_f16(*(const half8*)&kf[4*512 + lane*8], qf0, st2, 0,0,0);
        st2 = __builtin_amdgcn_mfma_f32_16x16x32_f16(*(const half8*)&kf[5*512 + lane*8], qf1, st2, 0,0,0);
        st3 = __builtin_amdgcn_mfma_f32_16x16x32_f16(*(const half8*)&kf[6*512 + lane*8], qf0, st3, 0,0,0);
        st3 = __builtin_amdgcn_mfma_f32_16x16x32_f16(*(const half8*)&kf[7*512 + lane*8], qf1, st3, 0,0,0);

        // ---- exp (no max-sub) + span mask on edge tiles ----
        float pv[4][4];
        float rsum = 0.0f;
        const bool edge = (kt < start) || (kt + 64 > endv);
        if (edge) {
            #pragma unroll
            for (int t = 0; t < 4; ++t) {
                const f32x4 sv = (t == 0) ? st0 : (t == 1) ? st1 : (t == 2) ? st2 : st3;
                #pragma unroll
                for (int r = 0; r < 4; ++r) {
                    const int col = kt + 16 * t + 4 * g + r;
                    const bool ok = (col >= start) && (col < endv);
                    const float e = ok ? __expf(sv[r] * SCALE) : 0.0f;
                    pv[t][r] = e;
                    rsum += e;
                }
            }
        } else {
            #pragma unroll
            for (int t = 0; t < 4; ++t) {
                const f32x4 sv = (t == 0) ? st0 : (t == 1) ? st1 : (t == 2) ? st2 : st3;
                #pragma unroll
                for (int r = 0; r < 4; ++r) {
                    const float e = __expf(sv[r] * SCALE);
                    pv[t][r] = e;
                    rsum += e;
                }
            }
        }
        rsum += __shfl_xor(rsum, 16, 64);
        rsum += __shfl_xor(rsum, 32, 64);
        l_i += rsum;

        // ---- pack P to fp16 and redistribute to A-frag layout ----
        unsigned pk[4][2];
        #pragma unroll
        for (int t = 0; t < 4; ++t) {
            pk[t][0] = pkrtz_u32(pv[t][0], pv[t][1]);
            pk[t][1] = pkrtz_u32(pv[t][2], pv[t][3]);
        }
        const int gsel = g >> 1;
        unsigned aw[2][4];
        #pragma unroll
        for (int cq = 0; cq < 2; ++cq) {
            #pragma unroll
            for (int wd = 0; wd < 4; ++wd) {
                const int srcLane = a + 16 * (2 * (g & 1) + (wd >> 1));
                const int lo2 = __shfl((int)pk[2 * cq    ][wd & 1], srcLane, 64);
                const int hi2 = __shfl((int)pk[2 * cq + 1][wd & 1], srcLane, 64);
                aw[cq][wd] = (unsigned)(gsel ? hi2 : lo2);
            }
        }
        const half8 pa0 = h8_from_u32x4(aw[0][0], aw[0][1], aw[0][2], aw[0][3]);
        const half8 pa1 = h8_from_u32x4(aw[1][0], aw[1][1], aw[1][2], aw[1][3]);

        // ---- O += P · V : D[q=4g+r][d=16td+a] ----
        o0 = __builtin_amdgcn_mfma_f32_16x16x32_f16(pa0, *(const half8*)&vf[0*512 + lane*8], o0, 0,0,0);
        o0 = __builtin_amdgcn_mfma_f32_16x16x32_f16(pa1, *(const half8*)&vf[1*512 + lane*8], o0, 0,0,0);
        o1 = __builtin_amdgcn_mfma_f32_16x16x32_f16(pa0, *(const half8*)&vf[2*512 + lane*8], o1, 0,0,0);
        o1 = __builtin_amdgcn_mfma_f32_16x16x32_f16(pa1, *(const half8*)&vf[3*512 + lane*8], o1, 0,0,0);
        o2 = __builtin_amdgcn_mfma_f32_16x16x32_f16(pa0, *(const half8*)&vf[4*512 + lane*8], o2, 0,0,0);
        o2 = __builtin_amdgcn_mfma_f32_16x16x32_f16(pa1, *(const half8*)&vf[5*512 + lane*8], o2, 0,0,0);
        o3 = __builtin_amdgcn_mfma_f32_16x16x32_f16(pa0, *(const half8*)&vf[6*512 + lane*8], o3, 0,0,0);
        o3 = __builtin_amdgcn_mfma_f32_16x16x32_f16(pa1, *(const half8*)&vf[7*512 + lane*8], o3, 0,0,0);

        asm volatile("" ::: "memory");
        __builtin_amdgcn_s_barrier();   // all waves done reading buf c
        c ^= 1;
    }
#undef STAGE

    // ---- store: valid rows O/l, invalid rows colmean ----
    const float inv = 1.0f / l_i;
    const float ir0 = __shfl(inv, 4 * g + 0, 64);
    const float ir1 = __shfl(inv, 4 * g + 1, 64);
    const float ir2 = __shfl(inv, 4 * g + 2, 64);
    const float ir3 = __shfl(inv, 4 * g + 3, 64);

    #pragma unroll
    for (int td = 0; td < 4; ++td) {
        const f32x4 ov = (td == 0) ? o0 : (td == 1) ? o1 : (td == 2) ? o2 : o3;
        const float cmv = cmb[16 * td + a];
        const float irs[4] = {ir0, ir1, ir2, ir3};
        #pragma unroll
        for (int r = 0; r < 4; ++r) {
            const int qr = q0 + 16 * w + 4 * g + r;
            const bool valid = (qr >= start) && (qr < endv);
            const float val = valid ? ov[r] * irs[r] : cmv;
            attb[(size_t)qr * DM_ + 16 * td + a] = (_Float16)val;
        }
    }
}

// ---------------------------------------------------------------------------
// Kernel 5: output projection via fp16 MFMA  (unchanged)
// ---------------------------------------------------------------------------
__global__ __launch_bounds__(256) void proj_mfma(
    const _Float16* __restrict__ A, const _Float16* __restrict__ Wt,
    const float* __restrict__ bias, float* __restrict__ out)
{
    const int m0 = blockIdx.x * 128;
    const int n0 = blockIdx.y * 64;
    const int tid = threadIdx.x;
    const int w = tid >> 6, lane = tid & 63;
    const int a = lane & 15, g = lane >> 4;
    const int mb = m0 + 32 * w;

    f32x4 d0[4] = {{0,0,0,0},{0,0,0,0},{0,0,0,0},{0,0,0,0}};
    f32x4 d1[4] = {{0,0,0,0},{0,0,0,0},{0,0,0,0},{0,0,0,0}};

    const _Float16* A0 = A + (size_t)(mb + a) * 256 + 8 * g;
    const _Float16* A1 = A + (size_t)(mb + 16 + a) * 256 + 8 * g;
    const _Float16* Wr0 = Wt + (size_t)(n0 +  0 + a) * 256 + 8 * g;
    const _Float16* Wr1 = Wt + (size_t)(n0 + 16 + a) * 256 + 8 * g;
    const _Float16* Wr2 = Wt + (size_t)(n0 + 32 + a) * 256 + 8 * g;
    const _Float16* Wr3 = Wt + (size_t)(n0 + 48 + a) * 256 + 8 * g;

    #pragma unroll
    for (int kc = 0; kc < 8; ++kc) {
        const half8 af0 = *(const half8*)(A0 + 32 * kc);
        const half8 af1 = *(const half8*)(A1 + 32 * kc);
        const half8 b0 = *(const half8*)(Wr0 + 32 * kc);
        const half8 b1 = *(const half8*)(Wr1 + 32 * kc);
        const half8 b2 = *(const half8*)(Wr2 + 32 * kc);
        const half8 b3 = *(const half8*)(Wr3 + 32 * kc);
        d0[0] = __builtin_amdgcn_mfma_f32_16x16x32_f16(af0, b0, d0[0], 0,0,0);
        d1[0] = __builtin_amdgcn_mfma_f32_16x16x32_f16(af1, b0, d1[0], 0,0,0);
        d0[1] = __builtin_amdgcn_mfma_f32_16x16x32_f16(af0, b1, d0[1], 0,0,0);
        d1[1] = __builtin_amdgcn_mfma_f32_16x16x32_f16(af1, b1, d1[1], 0,0,0);
        d0[2] = __builtin_amdgcn_mfma_f32_16x16x32_f16(af0, b2, d0[2], 0,0,0);
        d1[2] = __builtin_amdgcn_mfma_f32_16x16x32_f16(af1, b2, d1[2], 0,0,0);
        d0[3] = __builtin_amdgcn_mfma_f32_16x16x32_f16(af0, b3, d0[3], 0,0,0);
        d1[3] = __builtin_amdgcn_mfma_f32_16x16x32_f16(af1, b3, d1[3], 0,0,0);
    }

    #pragma unroll
    for (int t = 0; t < 2; ++t) {
        const int mrow = mb + 16 * t + 4 * g;
        #pragma unroll
        for (int nf = 0; nf < 4; ++nf) {
            const f32x4 dv = t == 0 ? d0[nf] : d1[nf];
            const int n = n0 + 16 * nf + a;
            const float bs = bias[n];
            #pragma unroll
            for (int r = 0; r < 4; ++r)
                out[(size_t)(mrow + r) * DM_ + n] = dv[r] + bs;
        }
    }
}

// ---------------------------------------------------------------------------
extern "C" void kernel_launch(void* const* d_in, const int* in_sizes, int n_in,
                              void* d_out, int out_size, void* d_ws, size_t ws_size,
                              hipStream_t stream)
{
    const float* x    = (const float*)d_in[0];
    const int*   mask = (const int*)d_in[1];
    const float* Wq   = (const float*)d_in[2];
    const float* bq   = (const float*)d_in[3];
    const float* Wk   = (const float*)d_in[4];
    const float* bk   = (const float*)d_in[5];
    const float* Wv   = (const float*)d_in[6];
    const float* bv   = (const float*)d_in[7];
    const float* Wo   = (const float*)d_in[8];
    const float* bo   = (const float*)d_in[9];
    float* out = (float*)d_out;

    char* ws = (char*)d_ws;
    size_t off = 0;
    int* bounds = (int*)ws;                 off += 256;
    float* cmv  = (float*)(ws + off);       off += (size_t)BH_ * DK_ * sizeof(float);
    off = (off + 255) & ~(size_t)255;
    const size_t h16_bytes = (size_t)BH_ * Nn * DK_ * sizeof(_Float16);   // 8 MB
    _Float16* xh  = (_Float16*)(ws + off); off += h16_bytes;
    _Float16* Qh  = (_Float16*)(ws + off); off += h16_bytes;
    _Float16* Kh  = (_Float16*)(ws + off); off += h16_bytes;
    _Float16* Vt  = (_Float16*)(ws + off); off += h16_bytes;
    _Float16* ath = (_Float16*)(ws + off); off += h16_bytes;
    _Float16* Wtq = (_Float16*)(ws + off); off += 256 * 256 * sizeof(_Float16);
    _Float16* Wtk = (_Float16*)(ws + off); off += 256 * 256 * sizeof(_Float16);
    _Float16* Wtv = (_Float16*)(ws + off); off += 256 * 256 * sizeof(_Float16);
    _Float16* Wto = (_Float16*)(ws + off); off += 256 * 256 * sizeof(_Float16);

    prep_kernel<<<2312, 256, 0, stream>>>(mask, bounds, x, xh,
                                          Wq, Wk, Wv, Wo, Wtq, Wtk, Wtv, Wto);

    dim3 g1(Bb * Nn / 128, DM_ / 64, 3);
    qkv_mfma<<<g1, 256, 0, stream>>>(xh, Wtq, bq, Wtk, bk, Wtv, bv, Qh, Kh, Vt);

    colmean_kernel<<<BH_, 256, 0, stream>>>(Vt, cmv);

    flash_mfma<<<1024, 256, 0, stream>>>(Qh, Kh, Vt, bounds, cmv, ath);

    dim3 g3(Bb * Nn / 128, DM_ / 64);
    proj_mfma<<<g3, 256, 0, stream>>>(ath, Wto, bo, out);
}

// Round 7
// 208.326 us; speedup vs baseline: 1.0027x; 1.0027x over previous
//
#include <hip/hip_runtime.h>
#include <hip/hip_bf16.h>
#include <math.h>

namespace {
constexpr int Bb  = 8;
constexpr int Nn  = 2048;
constexpr int DIN_ = 256;
constexpr int DM_  = 256;
constexpr int NH_  = 4;
constexpr int DK_  = 64;
constexpr int BH_  = Bb * NH_;
constexpr float SCALE = 0.125f;   // 1/sqrt(64)
}

typedef __attribute__((ext_vector_type(8))) _Float16 half8;
typedef __attribute__((ext_vector_type(2))) __fp16 fp16x2;
typedef __attribute__((ext_vector_type(4))) float f32x4;

static __device__ __forceinline__ unsigned pkrtz_u32(float a, float b) {
    union { fp16x2 h; unsigned u; } u;
    u.h = __builtin_amdgcn_cvt_pkrtz(a, b);
    return u.u;
}

static __device__ __forceinline__ half8 h8_from_u32x4(unsigned w0, unsigned w1,
                                                      unsigned w2, unsigned w3) {
    union { unsigned u[4]; half8 h; } u;
    u.u[0] = w0; u.u[1] = w1; u.u[2] = w2; u.u[3] = w3;
    return u.h;
}

// ---------------------------------------------------------------------------
// Kernel 1 (fused prep): blocks 0-7 bounds, 8-2055 convert_x, 2056-2311 convert_w
// ---------------------------------------------------------------------------
__global__ __launch_bounds__(256) void prep_kernel(
    const int* __restrict__ mask, int* __restrict__ bounds,
    const float* __restrict__ x, _Float16* __restrict__ xh,
    const float* __restrict__ W0, const float* __restrict__ W1,
    const float* __restrict__ W2, const float* __restrict__ W3,
    _Float16* __restrict__ T0, _Float16* __restrict__ T1,
    _Float16* __restrict__ T2, _Float16* __restrict__ T3)
{
    const int bid = blockIdx.x;
    const int tid = threadIdx.x;
    if (bid < 8) {
        const int b = bid;
        __shared__ int smin[256], smax[256];
        int lmin = Nn, lmax = -1;
        for (int i = tid; i < Nn; i += 256) {
            if (mask[b * Nn + i]) {
                if (i < lmin) lmin = i;
                if (i > lmax) lmax = i;
            }
        }
        smin[tid] = lmin; smax[tid] = lmax;
        __syncthreads();
        for (int s = 128; s > 0; s >>= 1) {
            if (tid < s) {
                smin[tid] = min(smin[tid], smin[tid + s]);
                smax[tid] = max(smax[tid], smax[tid + s]);
            }
            __syncthreads();
        }
        if (tid == 0) { bounds[b * 2] = smin[0]; bounds[b * 2 + 1] = smax[0]; }
    } else if (bid < 8 + 2048) {
        const size_t i = ((size_t)(bid - 8) * 256 + tid) * 8;
        float4 v0 = *(const float4*)&x[i];
        float4 v1 = *(const float4*)&x[i + 4];
        _Float16 h[8];
        h[0]=(_Float16)v0.x; h[1]=(_Float16)v0.y; h[2]=(_Float16)v0.z; h[3]=(_Float16)v0.w;
        h[4]=(_Float16)v1.x; h[5]=(_Float16)v1.y; h[6]=(_Float16)v1.z; h[7]=(_Float16)v1.w;
        *(uint4*)&xh[i] = *(const uint4*)h;
    } else {
        const int lin = bid - 2056;          // 0..255
        const int wsel = lin >> 6;
        const float* W; _Float16* T;
        switch (wsel) {
            case 0: W = W0; T = T0; break;
            case 1: W = W1; T = T1; break;
            case 2: W = W2; T = T2; break;
            default: W = W3; T = T3; break;
        }
        const int idx = (lin & 63) * 256 + tid;
        const int n = idx & 255;
        const int k0 = (idx >> 8) << 2;
        _Float16 h4[4];
        #pragma unroll
        for (int j = 0; j < 4; ++j) h4[j] = (_Float16)W[(size_t)(k0 + j) * 256 + n];
        *(uint2*)&T[(size_t)n * 256 + k0] = *(const uint2*)h4;
    }
}

// ---------------------------------------------------------------------------
// Kernel 2: QKV projection via fp16 MFMA.  (unchanged, proven)
// ---------------------------------------------------------------------------
__global__ __launch_bounds__(256) void qkv_mfma(
    const _Float16* __restrict__ xh,
    const _Float16* __restrict__ Wtq, const float* __restrict__ bq,
    const _Float16* __restrict__ Wtk, const float* __restrict__ bk,
    const _Float16* __restrict__ Wtv, const float* __restrict__ bv,
    _Float16* __restrict__ Qh, _Float16* __restrict__ Kh, _Float16* __restrict__ Vt)
{
    const int z = blockIdx.z;
    const _Float16* Wt; const float* bias;
    if (z == 0)      { Wt = Wtq; bias = bq; }
    else if (z == 1) { Wt = Wtk; bias = bk; }
    else             { Wt = Wtv; bias = bv; }

    const int m0 = blockIdx.x * 128;
    const int n0 = blockIdx.y * 64;
    const int tid = threadIdx.x;
    const int w = tid >> 6, lane = tid & 63;
    const int a = lane & 15, g = lane >> 4;
    const int mb = m0 + 32 * w;

    f32x4 d0[4] = {{0,0,0,0},{0,0,0,0},{0,0,0,0},{0,0,0,0}};
    f32x4 d1[4] = {{0,0,0,0},{0,0,0,0},{0,0,0,0},{0,0,0,0}};

    const _Float16* A0 = xh + (size_t)(mb + a) * 256 + 8 * g;
    const _Float16* A1 = xh + (size_t)(mb + 16 + a) * 256 + 8 * g;
    const _Float16* Wr0 = Wt + (size_t)(n0 +  0 + a) * 256 + 8 * g;
    const _Float16* Wr1 = Wt + (size_t)(n0 + 16 + a) * 256 + 8 * g;
    const _Float16* Wr2 = Wt + (size_t)(n0 + 32 + a) * 256 + 8 * g;
    const _Float16* Wr3 = Wt + (size_t)(n0 + 48 + a) * 256 + 8 * g;

    #pragma unroll
    for (int kc = 0; kc < 8; ++kc) {
        const half8 af0 = *(const half8*)(A0 + 32 * kc);
        const half8 af1 = *(const half8*)(A1 + 32 * kc);
        const half8 b0 = *(const half8*)(Wr0 + 32 * kc);
        const half8 b1 = *(const half8*)(Wr1 + 32 * kc);
        const half8 b2 = *(const half8*)(Wr2 + 32 * kc);
        const half8 b3 = *(const half8*)(Wr3 + 32 * kc);
        d0[0] = __builtin_amdgcn_mfma_f32_16x16x32_f16(af0, b0, d0[0], 0,0,0);
        d1[0] = __builtin_amdgcn_mfma_f32_16x16x32_f16(af1, b0, d1[0], 0,0,0);
        d0[1] = __builtin_amdgcn_mfma_f32_16x16x32_f16(af0, b1, d0[1], 0,0,0);
        d1[1] = __builtin_amdgcn_mfma_f32_16x16x32_f16(af1, b1, d1[1], 0,0,0);
        d0[2] = __builtin_amdgcn_mfma_f32_16x16x32_f16(af0, b2, d0[2], 0,0,0);
        d1[2] = __builtin_amdgcn_mfma_f32_16x16x32_f16(af1, b2, d1[2], 0,0,0);
        d0[3] = __builtin_amdgcn_mfma_f32_16x16x32_f16(af0, b3, d0[3], 0,0,0);
        d1[3] = __builtin_amdgcn_mfma_f32_16x16x32_f16(af1, b3, d1[3], 0,0,0);
    }

    #pragma unroll
    for (int t = 0; t < 2; ++t) {
        const int mrow = mb + 16 * t + 4 * g;
        #pragma unroll
        for (int nf = 0; nf < 4; ++nf) {
            const f32x4 dv = t == 0 ? d0[nf] : d1[nf];
            const int n = n0 + 16 * nf + a;
            const float bs = bias[n];
            const int bh = (mrow >> 11) * NH_ + (n >> 6);
            const int dk = n & 63;
            if (z < 2) {
                _Float16* out = z ? Kh : Qh;
                #pragma unroll
                for (int r = 0; r < 4; ++r) {
                    const int tok = (mrow + r) & 2047;
                    out[((size_t)bh * Nn + tok) * DK_ + dk] = (_Float16)(dv[r] + bs);
                }
            } else {
                const int tok = mrow & 2047;
                uint2 pk;
                pk.x = pkrtz_u32(dv[0] + bs, dv[1] + bs);
                pk.y = pkrtz_u32(dv[2] + bs, dv[3] + bs);
                *(uint2*)&Vt[((size_t)bh * DK_ + dk) * Nn + tok] = pk;
            }
        }
    }
}

// ---------------------------------------------------------------------------
// Kernel 3: column mean of V per (bh)  (unchanged).  cm layout [b][h][dk]=[b][256]
// ---------------------------------------------------------------------------
__global__ __launch_bounds__(256) void colmean_kernel(const _Float16* __restrict__ Vt,
                                                      float* __restrict__ cm) {
    const int bh = blockIdx.x;
    const int t = threadIdx.x;
    const int d = t >> 2, part = t & 3;
    const _Float16* src = Vt + ((size_t)bh * DK_ + d) * Nn + part * 512;
    float s = 0.f;
    for (int i = 0; i < 512; i += 8) {
        half8 v = *(const half8*)(src + i);
        #pragma unroll
        for (int j = 0; j < 8; ++j) s += (float)v[j];
    }
    __shared__ float red[64][4];
    red[d][part] = s;
    __syncthreads();
    if (part == 0)
        cm[bh * DK_ + d] = (red[d][0] + red[d][1] + red[d][2] + red[d][3]) * (1.0f / 2048.0f);
}

// ---------------------------------------------------------------------------
// Kernel 4: flash attention, fp16 MFMA, span-restricted, double-buffered,
// SPLIT-KV 2-way + balanced XCD swizzle.
// grid 2048: xcd=bid&7, rest=bid>>3, qb=rest&31, j=(rest>>5)&3, s=rest>>7,
// bh = j*8+xcd  (each XCD: 4 bh from different samples -> balanced + L2-local)
// Split s handles its contiguous half of the span tiles; stores UNNORMALIZED
// O (fp16, att layout) and l (fp32).  Combine kernel finishes.
// ---------------------------------------------------------------------------
__global__ __launch_bounds__(256) void flash_mfma(
    const _Float16* __restrict__ Q, const _Float16* __restrict__ K,
    const _Float16* __restrict__ Vt, const int* __restrict__ bounds,
    _Float16* __restrict__ Oh, float* __restrict__ lw)
{
    const int bid = blockIdx.x;
    const int xcd = bid & 7;
    const int rest = bid >> 3;
    const int qb  = rest & 31;
    const int j   = (rest >> 5) & 3;
    const int s   = rest >> 7;
    const int bh  = j * 8 + xcd;
    const int b  = bh >> 2, h = bh & 3;
    const int q0 = qb * 64;
    const int tid  = threadIdx.x;
    const int w    = tid >> 6;
    const int lane = tid & 63;
    const int a = lane & 15, g = lane >> 4;
    const int start = bounds[2 * b], endv = bounds[2 * b + 1];

    // fully-invalid q-block: combine fills colmean; nothing to do
    if (q0 + 63 < start || q0 >= endv) return;

    __shared__ __align__(16) _Float16 kfr[2][8][512];
    __shared__ __align__(16) _Float16 vfr[2][8][512];

    const _Float16* Qb = Q  + (size_t)bh * Nn * DK_;
    const _Float16* Kb = K  + (size_t)bh * Nn * DK_;
    const _Float16* Vb = Vt + (size_t)bh * DK_ * Nn;

    const int qrow = q0 + 16 * w + a;
    const half8 qf0 = *(const half8*)&Qb[(size_t)qrow * DK_ + 8 * g];
    const half8 qf1 = *(const half8*)&Qb[(size_t)qrow * DK_ + 32 + 8 * g];

    float l_i = 0.0f;
    f32x4 o0 = {0.f,0.f,0.f,0.f}, o1 = {0.f,0.f,0.f,0.f};
    f32x4 o2 = {0.f,0.f,0.f,0.f}, o3 = {0.f,0.f,0.f,0.f};

#define STAGE(cbuf, kt_) do {                                                        \
        _Pragma("unroll")                                                            \
        for (int ff = 0; ff < 2; ++ff) {                                             \
            const int f  = 2 * w + ff;                                               \
            const int tt = f >> 1, cc = f & 1;                                       \
            const _Float16* ks = &Kb[(size_t)((kt_) + 16 * tt + a) * DK_ + 32 * cc + 8 * g]; \
            __builtin_amdgcn_global_load_lds(                                        \
                (const __attribute__((address_space(1))) void*)ks,                   \
                (__attribute__((address_space(3))) void*)&kfr[cbuf][f][0], 16, 0, 0);\
            const _Float16* vs = &Vb[(size_t)(16 * tt + a) * Nn + (kt_) + 32 * cc + 8 * g]; \
            __builtin_amdgcn_global_load_lds(                                        \
                (const __attribute__((address_space(1))) void*)vs,                   \
                (__attribute__((address_space(3))) void*)&vfr[cbuf][f][0], 16, 0, 0);\
        }                                                                            \
    } while (0)

    // split tile range: [t0, t1) -> s=0: first n0 tiles, s=1: rest
    const int t0 = start >> 6, t1 = (endv + 63) >> 6;
    const int nt = t1 - t0;
    const int n0t = (nt + 1) >> 1;
    const int ts = (s == 0) ? t0 : t0 + n0t;
    const int te = (s == 0) ? t0 + n0t : t1;

    if (ts < te) {
        const int lo = ts * 64, hiend = te * 64;
        int c = 0;
        STAGE(0, lo);

        for (int kt = lo; kt < hiend; kt += 64) {
            const int nxt = kt + 64;
            if (nxt < hiend) {
                STAGE(c ^ 1, nxt);
                asm volatile("s_waitcnt vmcnt(4)" ::: "memory");
            } else {
                asm volatile("s_waitcnt vmcnt(0)" ::: "memory");
            }
            __builtin_amdgcn_s_barrier();

            const _Float16* kf = &kfr[c][0][0];
            const _Float16* vf = &vfr[c][0][0];

            // ---- S^T = K_tile · Q^T ----
            f32x4 st0 = {0.f,0.f,0.f,0.f}, st1 = {0.f,0.f,0.f,0.f};
            f32x4 st2 = {0.f,0.f,0.f,0.f}, st3 = {0.f,0.f,0.f,0.f};
            st0 = __builtin_amdgcn_mfma_f32_16x16x32_f16(*(const half8*)&kf[0*512 + lane*8], qf0, st0, 0,0,0);
            st0 = __builtin_amdgcn_mfma_f32_16x16x32_f16(*(const half8*)&kf[1*512 + lane*8], qf1, st0, 0,0,0);
            st1 = __builtin_amdgcn_mfma_f32_16x16x32_f16(*(const half8*)&kf[2*512 + lane*8], qf0, st1, 0,0,0);
            st1 = __builtin_amdgcn_mfma_f32_16x16x32_f16(*(const half8*)&kf[3*512 + lane*8], qf1, st1, 0,0,0);
            st2 = __builtin_amdgcn_mfma_f32_16x16x32_f16(*(const half8*)&kf[4*512 + lane*8], qf0, st2, 0,0,0);
            st2 = __builtin_amdgcn_mfma_f32_16x16x32_f16(*(const half8*)&kf[5*512 + lane*8], qf1, st2, 0,0,0);
            st3 = __builtin_amdgcn_mfma_f32_16x16x32_f16(*(const half8*)&kf[6*512 + lane*8], qf0, st3, 0,0,0);
            st3 = __builtin_amdgcn_mfma_f32_16x16x32_f16(*(const half8*)&kf[7*512 + lane*8], qf1, st3, 0,0,0);

            // ---- exp (no max-sub) + span mask on edge tiles ----
            float pv[4][4];
            float rsum = 0.0f;
            const bool edge = (kt < start) || (kt + 64 > endv);
            if (edge) {
                #pragma unroll
                for (int t = 0; t < 4; ++t) {
                    const f32x4 sv = (t == 0) ? st0 : (t == 1) ? st1 : (t == 2) ? st2 : st3;
                    #pragma unroll
                    for (int r = 0; r < 4; ++r) {
                        const int col = kt + 16 * t + 4 * g + r;
                        const bool ok = (col >= start) && (col < endv);
                        const float e = ok ? __expf(sv[r] * SCALE) : 0.0f;
                        pv[t][r] = e;
                        rsum += e;
                    }
                }
            } else {
                #pragma unroll
                for (int t = 0; t < 4; ++t) {
                    const f32x4 sv = (t == 0) ? st0 : (t == 1) ? st1 : (t == 2) ? st2 : st3;
                    #pragma unroll
                    for (int r = 0; r < 4; ++r) {
                        const float e = __expf(sv[r] * SCALE);
                        pv[t][r] = e;
                        rsum += e;
                    }
                }
            }
            rsum += __shfl_xor(rsum, 16, 64);
            rsum += __shfl_xor(rsum, 32, 64);
            l_i += rsum;

            // ---- pack P to fp16 and redistribute to A-frag layout ----
            unsigned pk[4][2];
            #pragma unroll
            for (int t = 0; t < 4; ++t) {
                pk[t][0] = pkrtz_u32(pv[t][0], pv[t][1]);
                pk[t][1] = pkrtz_u32(pv[t][2], pv[t][3]);
            }
            const int gsel = g >> 1;
            unsigned aw[2][4];
            #pragma unroll
            for (int cq = 0; cq < 2; ++cq) {
                #pragma unroll
                for (int wd = 0; wd < 4; ++wd) {
                    const int srcLane = a + 16 * (2 * (g & 1) + (wd >> 1));
                    const int lo2 = __shfl((int)pk[2 * cq    ][wd & 1], srcLane, 64);
                    const int hi2 = __shfl((int)pk[2 * cq + 1][wd & 1], srcLane, 64);
                    aw[cq][wd] = (unsigned)(gsel ? hi2 : lo2);
                }
            }
            const half8 pa0 = h8_from_u32x4(aw[0][0], aw[0][1], aw[0][2], aw[0][3]);
            const half8 pa1 = h8_from_u32x4(aw[1][0], aw[1][1], aw[1][2], aw[1][3]);

            // ---- O += P · V ----
            o0 = __builtin_amdgcn_mfma_f32_16x16x32_f16(pa0, *(const half8*)&vf[0*512 + lane*8], o0, 0,0,0);
            o0 = __builtin_amdgcn_mfma_f32_16x16x32_f16(pa1, *(const half8*)&vf[1*512 + lane*8], o0, 0,0,0);
            o1 = __builtin_amdgcn_mfma_f32_16x16x32_f16(pa0, *(const half8*)&vf[2*512 + lane*8], o1, 0,0,0);
            o1 = __builtin_amdgcn_mfma_f32_16x16x32_f16(pa1, *(const half8*)&vf[3*512 + lane*8], o1, 0,0,0);
            o2 = __builtin_amdgcn_mfma_f32_16x16x32_f16(pa0, *(const half8*)&vf[4*512 + lane*8], o2, 0,0,0);
            o2 = __builtin_amdgcn_mfma_f32_16x16x32_f16(pa1, *(const half8*)&vf[5*512 + lane*8], o2, 0,0,0);
            o3 = __builtin_amdgcn_mfma_f32_16x16x32_f16(pa0, *(const half8*)&vf[6*512 + lane*8], o3, 0,0,0);
            o3 = __builtin_amdgcn_mfma_f32_16x16x32_f16(pa1, *(const half8*)&vf[7*512 + lane*8], o3, 0,0,0);

            asm volatile("" ::: "memory");
            __builtin_amdgcn_s_barrier();
            c ^= 1;
        }
    }
#undef STAGE

    // ---- store partials: unnormalized O (fp16, att layout) + l (fp32) ----
    const size_t half = (size_t)Bb * Nn * DM_;
    _Float16* ob = Oh + (size_t)s * half + ((size_t)b * Nn) * DM_ + h * DK_;
    #pragma unroll
    for (int td = 0; td < 4; ++td) {
        const f32x4 ov = (td == 0) ? o0 : (td == 1) ? o1 : (td == 2) ? o2 : o3;
        #pragma unroll
        for (int r = 0; r < 4; ++r) {
            const int qr = q0 + 16 * w + 4 * g + r;
            ob[(size_t)qr * DM_ + 16 * td + a] = (_Float16)ov[r];
        }
    }
    if (g == 0) {
        const int tok = q0 + 16 * w + a;
        lw[(size_t)s * BH_ * Nn + (size_t)bh * Nn + tok] = l_i;
    }
}

// ---------------------------------------------------------------------------
// Kernel 4b: combine splits -> att fp16.  Valid rows: (O0+O1)/(l0+l1);
// invalid rows: colmean.  grid (Nn/64, Bb) x 256 threads.
// ---------------------------------------------------------------------------
__global__ __launch_bounds__(256) void combine_kernel(
    const _Float16* __restrict__ Oh, const float* __restrict__ lw,
    const int* __restrict__ bounds, const float* __restrict__ cm,
    _Float16* __restrict__ att)
{
    const int b  = blockIdx.y;
    const int q0 = blockIdx.x * 64;
    const int t  = threadIdx.x;
    const int row = q0 + (t >> 2);
    const int h   = t & 3;
    const int c0  = h * 64;
    const int start = bounds[2 * b], endv = bounds[2 * b + 1];
    const bool valid = (row >= start) && (row < endv);

    const size_t half = (size_t)Bb * Nn * DM_;
    const size_t rowoff = ((size_t)b * Nn + row) * DM_ + c0;

    float inv = 0.0f;
    if (valid) {
        const int bh = b * NH_ + h;
        const float l0 = lw[(size_t)bh * Nn + row];
        const float l1 = lw[(size_t)BH_ * Nn + (size_t)bh * Nn + row];
        inv = 1.0f / (l0 + l1);
    }

    #pragma unroll
    for (int jj = 0; jj < 64; jj += 8) {
        _Float16 o[8];
        if (valid) {
            half8 a0 = *(const half8*)&Oh[rowoff + jj];
            half8 a1 = *(const half8*)&Oh[half + rowoff + jj];
            #pragma unroll
            for (int k = 0; k < 8; ++k)
                o[k] = (_Float16)(((float)a0[k] + (float)a1[k]) * inv);
        } else {
            #pragma unroll
            for (int k = 0; k < 8; ++k)
                o[k] = (_Float16)cm[b * DM_ + c0 + jj + k];
        }
        *(uint4*)&att[rowoff + jj] = *(const uint4*)o;
    }
}

// ---------------------------------------------------------------------------
// Kernel 5: output projection via fp16 MFMA  (unchanged)
// ---------------------------------------------------------------------------
__global__ __launch_bounds__(256) void proj_mfma(
    const _Float16* __restrict__ A, const _Float16* __restrict__ Wt,
    const float* __restrict__ bias, float* __restrict__ out)
{
    const int m0 = blockIdx.x * 128;
    const int n0 = blockIdx.y * 64;
    const int tid = threadIdx.x;
    const int w = tid >> 6, lane = tid & 63;
    const int a = lane & 15, g = lane >> 4;
    const int mb = m0 + 32 * w;

    f32x4 d0[4] = {{0,0,0,0},{0,0,0,0},{0,0,0,0},{0,0,0,0}};
    f32x4 d1[4] = {{0,0,0,0},{0,0,0,0},{0,0,0,0},{0,0,0,0}};

    const _Float16* A0 = A + (size_t)(mb + a) * 256 + 8 * g;
    const _Float16* A1 = A + (size_t)(mb + 16 + a) * 256 + 8 * g;
    const _Float16* Wr0 = Wt + (size_t)(n0 +  0 + a) * 256 + 8 * g;
    const _Float16* Wr1 = Wt + (size_t)(n0 + 16 + a) * 256 + 8 * g;
    const _Float16* Wr2 = Wt + (size_t)(n0 + 32 + a) * 256 + 8 * g;
    const _Float16* Wr3 = Wt + (size_t)(n0 + 48 + a) * 256 + 8 * g;

    #pragma unroll
    for (int kc = 0; kc < 8; ++kc) {
        const half8 af0 = *(const half8*)(A0 + 32 * kc);
        const half8 af1 = *(const half8*)(A1 + 32 * kc);
        const half8 b0 = *(const half8*)(Wr0 + 32 * kc);
        const half8 b1 = *(const half8*)(Wr1 + 32 * kc);
        const half8 b2 = *(const half8*)(Wr2 + 32 * kc);
        const half8 b3 = *(const half8*)(Wr3 + 32 * kc);
        d0[0] = __builtin_amdgcn_mfma_f32_16x16x32_f16(af0, b0, d0[0], 0,0,0);
        d1[0] = __builtin_amdgcn_mfma_f32_16x16x32_f16(af1, b0, d1[0], 0,0,0);
        d0[1] = __builtin_amdgcn_mfma_f32_16x16x32_f16(af0, b1, d0[1], 0,0,0);
        d1[1] = __builtin_amdgcn_mfma_f32_16x16x32_f16(af1, b1, d1[1], 0,0,0);
        d0[2] = __builtin_amdgcn_mfma_f32_16x16x32_f16(af0, b2, d0[2], 0,0,0);
        d1[2] = __builtin_amdgcn_mfma_f32_16x16x32_f16(af1, b2, d1[2], 0,0,0);
        d0[3] = __builtin_amdgcn_mfma_f32_16x16x32_f16(af0, b3, d0[3], 0,0,0);
        d1[3] = __builtin_amdgcn_mfma_f32_16x16x32_f16(af1, b3, d1[3], 0,0,0);
    }

    #pragma unroll
    for (int t = 0; t < 2; ++t) {
        const int mrow = mb + 16 * t + 4 * g;
        #pragma unroll
        for (int nf = 0; nf < 4; ++nf) {
            const f32x4 dv = t == 0 ? d0[nf] : d1[nf];
            const int n = n0 + 16 * nf + a;
            const float bs = bias[n];
            #pragma unroll
            for (int r = 0; r < 4; ++r)
                out[(size_t)(mrow + r) * DM_ + n] = dv[r] + bs;
        }
    }
}

// ---------------------------------------------------------------------------
extern "C" void kernel_launch(void* const* d_in, const int* in_sizes, int n_in,
                              void* d_out, int out_size, void* d_ws, size_t ws_size,
                              hipStream_t stream)
{
    const float* x    = (const float*)d_in[0];
    const int*   mask = (const int*)d_in[1];
    const float* Wq   = (const float*)d_in[2];
    const float* bq   = (const float*)d_in[3];
    const float* Wk   = (const float*)d_in[4];
    const float* bk   = (const float*)d_in[5];
    const float* Wv   = (const float*)d_in[6];
    const float* bv   = (const float*)d_in[7];
    const float* Wo   = (const float*)d_in[8];
    const float* bo   = (const float*)d_in[9];
    float* out = (float*)d_out;

    char* ws = (char*)d_ws;
    size_t off = 0;
    int* bounds = (int*)ws;                 off += 256;
    float* cmv  = (float*)(ws + off);       off += (size_t)BH_ * DK_ * sizeof(float);
    off = (off + 255) & ~(size_t)255;
    float* lw   = (float*)(ws + off);       off += (size_t)2 * BH_ * Nn * sizeof(float);
    const size_t h16_bytes = (size_t)BH_ * Nn * DK_ * sizeof(_Float16);   // 8 MB
    _Float16* xh  = (_Float16*)(ws + off); off += h16_bytes;
    _Float16* Qh  = (_Float16*)(ws + off); off += h16_bytes;
    _Float16* Kh  = (_Float16*)(ws + off); off += h16_bytes;
    _Float16* Vt  = (_Float16*)(ws + off); off += h16_bytes;
    _Float16* Oh  = (_Float16*)(ws + off); off += 2 * h16_bytes;   // 2 splits
    _Float16* ath = (_Float16*)(ws + off); off += h16_bytes;
    _Float16* Wtq = (_Float16*)(ws + off); off += 256 * 256 * sizeof(_Float16);
    _Float16* Wtk = (_Float16*)(ws + off); off += 256 * 256 * sizeof(_Float16);
    _Float16* Wtv = (_Float16*)(ws + off); off += 256 * 256 * sizeof(_Float16);
    _Float16* Wto = (_Float16*)(ws + off); off += 256 * 256 * sizeof(_Float16);

    prep_kernel<<<2312, 256, 0, stream>>>(mask, bounds, x, xh,
                                          Wq, Wk, Wv, Wo, Wtq, Wtk, Wtv, Wto);

    dim3 g1(Bb * Nn / 128, DM_ / 64, 3);
    qkv_mfma<<<g1, 256, 0, stream>>>(xh, Wtq, bq, Wtk, bk, Wtv, bv, Qh, Kh, Vt);

    colmean_kernel<<<BH_, 256, 0, stream>>>(Vt, cmv);

    flash_mfma<<<2048, 256, 0, stream>>>(Qh, Kh, Vt, bounds, Oh, lw);

    dim3 gc(Nn / 64, Bb);
    combine_kernel<<<gc, 256, 0, stream>>>(Oh, lw, bounds, cmv, ath);

    dim3 g3(Bb * Nn / 128, DM_ / 64);
    proj_mfma<<<g3, 256, 0, stream>>>(ath, Wto, bo, out);
}

// Round 8
// 183.944 us; speedup vs baseline: 1.1357x; 1.1325x over previous
//
#include <hip/hip_runtime.h>
#include <hip/hip_bf16.h>
#include <math.h>

namespace {
constexpr int Bb  = 8;
constexpr int Nn  = 2048;
constexpr int DIN_ = 256;
constexpr int DM_  = 256;
constexpr int NH_  = 4;
constexpr int DK_  = 64;
constexpr int BH_  = Bb * NH_;
constexpr float SCALE = 0.125f;   // 1/sqrt(64)
}

typedef __attribute__((ext_vector_type(8))) _Float16 half8;
typedef __attribute__((ext_vector_type(2))) __fp16 fp16x2;
typedef __attribute__((ext_vector_type(4))) float f32x4;

static __device__ __forceinline__ unsigned pkrtz_u32(float a, float b) {
    union { fp16x2 h; unsigned u; } u;
    u.h = __builtin_amdgcn_cvt_pkrtz(a, b);
    return u.u;
}

static __device__ __forceinline__ half8 h8_from_u32x4(unsigned w0, unsigned w1,
                                                      unsigned w2, unsigned w3) {
    union { unsigned u[4]; half8 h; } u;
    u.u[0] = w0; u.u[1] = w1; u.u[2] = w2; u.u[3] = w3;
    return u.h;
}

// ---------------------------------------------------------------------------
// Kernel 1 (prep): blocks 0-7 bounds; 8-263 weight transpose+convert.
// x conversion is FUSED into qkv_mfma staging (removes 25MB round-trip).
// ---------------------------------------------------------------------------
__global__ __launch_bounds__(256) void prep_kernel(
    const int* __restrict__ mask, int* __restrict__ bounds,
    const float* __restrict__ W0, const float* __restrict__ W1,
    const float* __restrict__ W2, const float* __restrict__ W3,
    _Float16* __restrict__ T0, _Float16* __restrict__ T1,
    _Float16* __restrict__ T2, _Float16* __restrict__ T3)
{
    const int bid = blockIdx.x;
    const int tid = threadIdx.x;
    if (bid < 8) {
        const int b = bid;
        __shared__ int smin[256], smax[256];
        int lmin = Nn, lmax = -1;
        for (int i = tid; i < Nn; i += 256) {
            if (mask[b * Nn + i]) {
                if (i < lmin) lmin = i;
                if (i > lmax) lmax = i;
            }
        }
        smin[tid] = lmin; smax[tid] = lmax;
        __syncthreads();
        for (int s = 128; s > 0; s >>= 1) {
            if (tid < s) {
                smin[tid] = min(smin[tid], smin[tid + s]);
                smax[tid] = max(smax[tid], smax[tid + s]);
            }
            __syncthreads();
        }
        if (tid == 0) { bounds[b * 2] = smin[0]; bounds[b * 2 + 1] = smax[0]; }
    } else {
        const int lin = bid - 8;             // 0..255
        const int wsel = lin >> 6;
        const float* W; _Float16* T;
        switch (wsel) {
            case 0: W = W0; T = T0; break;
            case 1: W = W1; T = T1; break;
            case 2: W = W2; T = T2; break;
            default: W = W3; T = T3; break;
        }
        const int idx = (lin & 63) * 256 + tid;
        const int n = idx & 255;
        const int k0 = (idx >> 8) << 2;
        _Float16 h4[4];
        #pragma unroll
        for (int j = 0; j < 4; ++j) h4[j] = (_Float16)W[(size_t)(k0 + j) * 256 + n];
        *(uint2*)&T[(size_t)n * 256 + k0] = *(const uint2*)h4;
    }
}

// ---------------------------------------------------------------------------
// Kernel 2: QKV projection, LDS-staged fp16 MFMA GEMM with fused x-convert.
// grid (128, 12): m0 = bx*128, zsel = by>>2 (Q/K/V), n0 = (by&3)*64.
// A (x): reg-staged fp32->fp16 with XOR-swizzled ds_write_b128.
// B (Wt): global_load_lds with pre-swizzled per-lane SOURCE (linear dest).
// Q/K use SWAPPED operands (D rows = n) -> uint2 stores into [bh][tok][dk];
// V unswapped (D rows = tok) -> uint2 stores into Vt [bh][dk][tok].
// ---------------------------------------------------------------------------
__global__ __launch_bounds__(256) void qkv_mfma(
    const float* __restrict__ x,
    const _Float16* __restrict__ Wtq, const float* __restrict__ bq,
    const _Float16* __restrict__ Wtk, const float* __restrict__ bk,
    const _Float16* __restrict__ Wtv, const float* __restrict__ bv,
    _Float16* __restrict__ Qh, _Float16* __restrict__ Kh, _Float16* __restrict__ Vt)
{
    const int zsel = blockIdx.y >> 2;
    const int n0 = (blockIdx.y & 3) * 64;
    const int m0 = blockIdx.x * 128;
    const _Float16* Wt; const float* bias;
    if (zsel == 0)      { Wt = Wtq; bias = bq; }
    else if (zsel == 1) { Wt = Wtk; bias = bk; }
    else                { Wt = Wtv; bias = bv; }

    const int tid = threadIdx.x;
    const int w = tid >> 6, lane = tid & 63;
    const int a = lane & 15, g = lane >> 4;
    const int b = m0 >> 11;                  // 128-row tile never crosses batch

    __shared__ __align__(16) _Float16 As[128 * 64];   // 16KB, swizzled rows of 128B
    __shared__ __align__(16) _Float16 Bs[64 * 64];    // 8KB

    f32x4 acc[4][2] = {{{0,0,0,0},{0,0,0,0}},{{0,0,0,0},{0,0,0,0}},
                       {{0,0,0,0},{0,0,0,0}},{{0,0,0,0},{0,0,0,0}}};

    for (int step = 0; step < 4; ++step) {
        const int k0 = step * 64;
        // ---- stage A: convert x fp32->fp16 (RTE), swizzled ds_write ----
        {
            const int rb = tid >> 3, fc = tid & 7;
            #pragma unroll
            for (int p = 0; p < 4; ++p) {
                const int row = p * 32 + rb;
                const float4 v0 = *(const float4*)&x[(size_t)(m0 + row) * 256 + k0 + fc * 8];
                const float4 v1 = *(const float4*)&x[(size_t)(m0 + row) * 256 + k0 + fc * 8 + 4];
                _Float16 h[8];
                h[0]=(_Float16)v0.x; h[1]=(_Float16)v0.y; h[2]=(_Float16)v0.z; h[3]=(_Float16)v0.w;
                h[4]=(_Float16)v1.x; h[5]=(_Float16)v1.y; h[6]=(_Float16)v1.z; h[7]=(_Float16)v1.w;
                const int byo = (fc * 16) ^ ((row & 7) << 4);
                *(uint4*)((char*)As + row * 128 + byo) = *(const uint4*)h;
            }
        }
        // ---- stage B: global_load_lds, pre-swizzled source, linear dest ----
        #pragma unroll
        for (int i = 0; i < 2; ++i) {
            const int f = 2 * w + i;                       // 0..7
            const int rowl = f * 8 + (lane >> 3);          // 0..63
            const int byo = ((lane & 7) * 16) ^ ((rowl & 7) << 4);
            const char* src = (const char*)(Wt + (size_t)(n0 + rowl) * 256 + k0) + byo;
            __builtin_amdgcn_global_load_lds(
                (const __attribute__((address_space(1))) void*)src,
                (__attribute__((address_space(3))) void*)((char*)Bs + f * 1024), 16, 0, 0);
        }
        __syncthreads();

        // ---- compute: 2 k-chunks of 32 ----
        #pragma unroll
        for (int kc = 0; kc < 2; ++kc) {
            half8 xf[2], wf[4];
            #pragma unroll
            for (int tt = 0; tt < 2; ++tt) {
                const int row = 32 * w + 16 * tt + a;
                const int byo = (kc * 64 + g * 16) ^ ((row & 7) << 4);
                xf[tt] = *(const half8*)((const char*)As + row * 128 + byo);
            }
            #pragma unroll
            for (int nf = 0; nf < 4; ++nf) {
                const int row = 16 * nf + a;
                const int byo = (kc * 64 + g * 16) ^ ((row & 7) << 4);
                wf[nf] = *(const half8*)((const char*)Bs + row * 128 + byo);
            }
            if (zsel < 2) {
                #pragma unroll
                for (int nf = 0; nf < 4; ++nf)
                    #pragma unroll
                    for (int tt = 0; tt < 2; ++tt)
                        acc[nf][tt] = __builtin_amdgcn_mfma_f32_16x16x32_f16(wf[nf], xf[tt], acc[nf][tt], 0,0,0);
            } else {
                #pragma unroll
                for (int nf = 0; nf < 4; ++nf)
                    #pragma unroll
                    for (int tt = 0; tt < 2; ++tt)
                        acc[nf][tt] = __builtin_amdgcn_mfma_f32_16x16x32_f16(xf[tt], wf[nf], acc[nf][tt], 0,0,0);
            }
        }
        __syncthreads();
    }

    // ---- stores ----
    if (zsel < 2) {
        // D[n = n0+16nf+4g+r][tok = m0+32w+16tt+a]
        _Float16* out = zsel ? Kh : Qh;
        #pragma unroll
        for (int nf = 0; nf < 4; ++nf) {
            const int nb = n0 + 16 * nf + 4 * g;
            const f32x4 bi = *(const f32x4*)&bias[nb];
            const int h = nb >> 6, dkb = nb & 63;
            #pragma unroll
            for (int tt = 0; tt < 2; ++tt) {
                const int tok = (m0 + 32 * w + 16 * tt + a) & 2047;
                const f32x4 d = acc[nf][tt];
                _Float16 q4[4];
                q4[0] = (_Float16)(d[0] + bi[0]);
                q4[1] = (_Float16)(d[1] + bi[1]);
                q4[2] = (_Float16)(d[2] + bi[2]);
                q4[3] = (_Float16)(d[3] + bi[3]);
                *(uint2*)&out[(((size_t)(b * NH_ + h)) * Nn + tok) * DK_ + dkb] = *(const uint2*)q4;
            }
        }
    } else {
        // D[tok = m0+32w+16tt+4g+r][n = n0+16nf+a]
        const int h = n0 >> 6;
        #pragma unroll
        for (int nf = 0; nf < 4; ++nf) {
            const int n = n0 + 16 * nf + a;
            const float bs = bias[n];
            const int dk = 16 * nf + a;
            #pragma unroll
            for (int tt = 0; tt < 2; ++tt) {
                const int tokb = (m0 + 32 * w + 16 * tt + 4 * g) & 2047;
                const f32x4 d = acc[nf][tt];
                uint2 pk;
                pk.x = pkrtz_u32(d[0] + bs, d[1] + bs);
                pk.y = pkrtz_u32(d[2] + bs, d[3] + bs);
                *(uint2*)&Vt[(((size_t)(b * NH_ + h)) * DK_ + dk) * Nn + tokb] = pk;
            }
        }
    }
}

// ---------------------------------------------------------------------------
// Kernel 3: column mean of V per (bh)  (unchanged)
// ---------------------------------------------------------------------------
__global__ __launch_bounds__(256) void colmean_kernel(const _Float16* __restrict__ Vt,
                                                      float* __restrict__ cm) {
    const int bh = blockIdx.x;
    const int t = threadIdx.x;
    const int d = t >> 2, part = t & 3;
    const _Float16* src = Vt + ((size_t)bh * DK_ + d) * Nn + part * 512;
    float s = 0.f;
    for (int i = 0; i < 512; i += 8) {
        half8 v = *(const half8*)(src + i);
        #pragma unroll
        for (int j = 0; j < 8; ++j) s += (float)v[j];
    }
    __shared__ float red[64][4];
    red[d][part] = s;
    __syncthreads();
    if (part == 0)
        cm[bh * DK_ + d] = (red[d][0] + red[d][1] + red[d][2] + red[d][3]) * (1.0f / 2048.0f);
}

// ---------------------------------------------------------------------------
// Kernel 4: flash attention (R7 structure, proven) + s_setprio around MFMA.
// ---------------------------------------------------------------------------
__global__ __launch_bounds__(256) void flash_mfma(
    const _Float16* __restrict__ Q, const _Float16* __restrict__ K,
    const _Float16* __restrict__ Vt, const int* __restrict__ bounds,
    _Float16* __restrict__ Oh, float* __restrict__ lw)
{
    const int bid = blockIdx.x;
    const int xcd = bid & 7;
    const int rest = bid >> 3;
    const int qb  = rest & 31;
    const int j   = (rest >> 5) & 3;
    const int s   = rest >> 7;
    const int bh  = j * 8 + xcd;
    const int b  = bh >> 2, h = bh & 3;
    const int q0 = qb * 64;
    const int tid  = threadIdx.x;
    const int w    = tid >> 6;
    const int lane = tid & 63;
    const int a = lane & 15, g = lane >> 4;
    const int start = bounds[2 * b], endv = bounds[2 * b + 1];

    if (q0 + 63 < start || q0 >= endv) return;

    __shared__ __align__(16) _Float16 kfr[2][8][512];
    __shared__ __align__(16) _Float16 vfr[2][8][512];

    const _Float16* Qb = Q  + (size_t)bh * Nn * DK_;
    const _Float16* Kb = K  + (size_t)bh * Nn * DK_;
    const _Float16* Vb = Vt + (size_t)bh * DK_ * Nn;

    const int qrow = q0 + 16 * w + a;
    const half8 qf0 = *(const half8*)&Qb[(size_t)qrow * DK_ + 8 * g];
    const half8 qf1 = *(const half8*)&Qb[(size_t)qrow * DK_ + 32 + 8 * g];

    float l_i = 0.0f;
    f32x4 o0 = {0.f,0.f,0.f,0.f}, o1 = {0.f,0.f,0.f,0.f};
    f32x4 o2 = {0.f,0.f,0.f,0.f}, o3 = {0.f,0.f,0.f,0.f};

#define STAGE(cbuf, kt_) do {                                                        \
        _Pragma("unroll")                                                            \
        for (int ff = 0; ff < 2; ++ff) {                                             \
            const int f  = 2 * w + ff;                                               \
            const int tt = f >> 1, cc = f & 1;                                       \
            const _Float16* ks = &Kb[(size_t)((kt_) + 16 * tt + a) * DK_ + 32 * cc + 8 * g]; \
            __builtin_amdgcn_global_load_lds(                                        \
                (const __attribute__((address_space(1))) void*)ks,                   \
                (__attribute__((address_space(3))) void*)&kfr[cbuf][f][0], 16, 0, 0);\
            const _Float16* vs = &Vb[(size_t)(16 * tt + a) * Nn + (kt_) + 32 * cc + 8 * g]; \
            __builtin_amdgcn_global_load_lds(                                        \
                (const __attribute__((address_space(1))) void*)vs,                   \
                (__attribute__((address_space(3))) void*)&vfr[cbuf][f][0], 16, 0, 0);\
        }                                                                            \
    } while (0)

    const int t0 = start >> 6, t1 = (endv + 63) >> 6;
    const int nt = t1 - t0;
    const int n0t = (nt + 1) >> 1;
    const int ts = (s == 0) ? t0 : t0 + n0t;
    const int te = (s == 0) ? t0 + n0t : t1;

    if (ts < te) {
        const int lo = ts * 64, hiend = te * 64;
        int c = 0;
        STAGE(0, lo);

        for (int kt = lo; kt < hiend; kt += 64) {
            const int nxt = kt + 64;
            if (nxt < hiend) {
                STAGE(c ^ 1, nxt);
                asm volatile("s_waitcnt vmcnt(4)" ::: "memory");
            } else {
                asm volatile("s_waitcnt vmcnt(0)" ::: "memory");
            }
            __builtin_amdgcn_s_barrier();

            const _Float16* kf = &kfr[c][0][0];
            const _Float16* vf = &vfr[c][0][0];

            f32x4 st0 = {0.f,0.f,0.f,0.f}, st1 = {0.f,0.f,0.f,0.f};
            f32x4 st2 = {0.f,0.f,0.f,0.f}, st3 = {0.f,0.f,0.f,0.f};
            __builtin_amdgcn_s_setprio(1);
            st0 = __builtin_amdgcn_mfma_f32_16x16x32_f16(*(const half8*)&kf[0*512 + lane*8], qf0, st0, 0,0,0);
            st0 = __builtin_amdgcn_mfma_f32_16x16x32_f16(*(const half8*)&kf[1*512 + lane*8], qf1, st0, 0,0,0);
            st1 = __builtin_amdgcn_mfma_f32_16x16x32_f16(*(const half8*)&kf[2*512 + lane*8], qf0, st1, 0,0,0);
            st1 = __builtin_amdgcn_mfma_f32_16x16x32_f16(*(const half8*)&kf[3*512 + lane*8], qf1, st1, 0,0,0);
            st2 = __builtin_amdgcn_mfma_f32_16x16x32_f16(*(const half8*)&kf[4*512 + lane*8], qf0, st2, 0,0,0);
            st2 = __builtin_amdgcn_mfma_f32_16x16x32_f16(*(const half8*)&kf[5*512 + lane*8], qf1, st2, 0,0,0);
            st3 = __builtin_amdgcn_mfma_f32_16x16x32_f16(*(const half8*)&kf[6*512 + lane*8], qf0, st3, 0,0,0);
            st3 = __builtin_amdgcn_mfma_f32_16x16x32_f16(*(const half8*)&kf[7*512 + lane*8], qf1, st3, 0,0,0);
            __builtin_amdgcn_s_setprio(0);

            float pv[4][4];
            float rsum = 0.0f;
            const bool edge = (kt < start) || (kt + 64 > endv);
            if (edge) {
                #pragma unroll
                for (int t = 0; t < 4; ++t) {
                    const f32x4 sv = (t == 0) ? st0 : (t == 1) ? st1 : (t == 2) ? st2 : st3;
                    #pragma unroll
                    for (int r = 0; r < 4; ++r) {
                        const int col = kt + 16 * t + 4 * g + r;
                        const bool ok = (col >= start) && (col < endv);
                        const float e = ok ? __expf(sv[r] * SCALE) : 0.0f;
                        pv[t][r] = e;
                        rsum += e;
                    }
                }
            } else {
                #pragma unroll
                for (int t = 0; t < 4; ++t) {
                    const f32x4 sv = (t == 0) ? st0 : (t == 1) ? st1 : (t == 2) ? st2 : st3;
                    #pragma unroll
                    for (int r = 0; r < 4; ++r) {
                        const float e = __expf(sv[r] * SCALE);
                        pv[t][r] = e;
                        rsum += e;
                    }
                }
            }
            rsum += __shfl_xor(rsum, 16, 64);
            rsum += __shfl_xor(rsum, 32, 64);
            l_i += rsum;

            unsigned pk[4][2];
            #pragma unroll
            for (int t = 0; t < 4; ++t) {
                pk[t][0] = pkrtz_u32(pv[t][0], pv[t][1]);
                pk[t][1] = pkrtz_u32(pv[t][2], pv[t][3]);
            }
            const int gsel = g >> 1;
            unsigned aw[2][4];
            #pragma unroll
            for (int cq = 0; cq < 2; ++cq) {
                #pragma unroll
                for (int wd = 0; wd < 4; ++wd) {
                    const int srcLane = a + 16 * (2 * (g & 1) + (wd >> 1));
                    const int lo2 = __shfl((int)pk[2 * cq    ][wd & 1], srcLane, 64);
                    const int hi2 = __shfl((int)pk[2 * cq + 1][wd & 1], srcLane, 64);
                    aw[cq][wd] = (unsigned)(gsel ? hi2 : lo2);
                }
            }
            const half8 pa0 = h8_from_u32x4(aw[0][0], aw[0][1], aw[0][2], aw[0][3]);
            const half8 pa1 = h8_from_u32x4(aw[1][0], aw[1][1], aw[1][2], aw[1][3]);

            __builtin_amdgcn_s_setprio(1);
            o0 = __builtin_amdgcn_mfma_f32_16x16x32_f16(pa0, *(const half8*)&vf[0*512 + lane*8], o0, 0,0,0);
            o0 = __builtin_amdgcn_mfma_f32_16x16x32_f16(pa1, *(const half8*)&vf[1*512 + lane*8], o0, 0,0,0);
            o1 = __builtin_amdgcn_mfma_f32_16x16x32_f16(pa0, *(const half8*)&vf[2*512 + lane*8], o1, 0,0,0);
            o1 = __builtin_amdgcn_mfma_f32_16x16x32_f16(pa1, *(const half8*)&vf[3*512 + lane*8], o1, 0,0,0);
            o2 = __builtin_amdgcn_mfma_f32_16x16x32_f16(pa0, *(const half8*)&vf[4*512 + lane*8], o2, 0,0,0);
            o2 = __builtin_amdgcn_mfma_f32_16x16x32_f16(pa1, *(const half8*)&vf[5*512 + lane*8], o2, 0,0,0);
            o3 = __builtin_amdgcn_mfma_f32_16x16x32_f16(pa0, *(const half8*)&vf[6*512 + lane*8], o3, 0,0,0);
            o3 = __builtin_amdgcn_mfma_f32_16x16x32_f16(pa1, *(const half8*)&vf[7*512 + lane*8], o3, 0,0,0);
            __builtin_amdgcn_s_setprio(0);

            asm volatile("" ::: "memory");
            __builtin_amdgcn_s_barrier();
            c ^= 1;
        }
    }
#undef STAGE

    const size_t half = (size_t)Bb * Nn * DM_;
    _Float16* ob = Oh + (size_t)s * half + ((size_t)b * Nn) * DM_ + h * DK_;
    #pragma unroll
    for (int td = 0; td < 4; ++td) {
        const f32x4 ov = (td == 0) ? o0 : (td == 1) ? o1 : (td == 2) ? o2 : o3;
        #pragma unroll
        for (int r = 0; r < 4; ++r) {
            const int qr = q0 + 16 * w + 4 * g + r;
            ob[(size_t)qr * DM_ + 16 * td + a] = (_Float16)ov[r];
        }
    }
    if (g == 0) {
        const int tok = q0 + 16 * w + a;
        lw[(size_t)s * BH_ * Nn + (size_t)bh * Nn + tok] = l_i;
    }
}

// ---------------------------------------------------------------------------
// Kernel 4b: combine splits -> att fp16  (unchanged)
// ---------------------------------------------------------------------------
__global__ __launch_bounds__(256) void combine_kernel(
    const _Float16* __restrict__ Oh, const float* __restrict__ lw,
    const int* __restrict__ bounds, const float* __restrict__ cm,
    _Float16* __restrict__ att)
{
    const int b  = blockIdx.y;
    const int q0 = blockIdx.x * 64;
    const int t  = threadIdx.x;
    const int row = q0 + (t >> 2);
    const int h   = t & 3;
    const int c0  = h * 64;
    const int start = bounds[2 * b], endv = bounds[2 * b + 1];
    const bool valid = (row >= start) && (row < endv);

    const size_t half = (size_t)Bb * Nn * DM_;
    const size_t rowoff = ((size_t)b * Nn + row) * DM_ + c0;

    float inv = 0.0f;
    if (valid) {
        const int bh = b * NH_ + h;
        const float l0 = lw[(size_t)bh * Nn + row];
        const float l1 = lw[(size_t)BH_ * Nn + (size_t)bh * Nn + row];
        inv = 1.0f / (l0 + l1);
    }

    #pragma unroll
    for (int jj = 0; jj < 64; jj += 8) {
        _Float16 o[8];
        if (valid) {
            half8 a0 = *(const half8*)&Oh[rowoff + jj];
            half8 a1 = *(const half8*)&Oh[half + rowoff + jj];
            #pragma unroll
            for (int k = 0; k < 8; ++k)
                o[k] = (_Float16)(((float)a0[k] + (float)a1[k]) * inv);
        } else {
            #pragma unroll
            for (int k = 0; k < 8; ++k)
                o[k] = (_Float16)cm[b * DM_ + c0 + jj + k];
        }
        *(uint4*)&att[rowoff + jj] = *(const uint4*)o;
    }
}

// ---------------------------------------------------------------------------
// Kernel 5: output projection, LDS-staged fp16 MFMA (same structure as qkv).
// grid (128, 4).  A = ath (fp16, global_load_lds pre-swizzled), B = Wto.
// ---------------------------------------------------------------------------
__global__ __launch_bounds__(256) void proj_mfma(
    const _Float16* __restrict__ A, const _Float16* __restrict__ Wt,
    const float* __restrict__ bias, float* __restrict__ out)
{
    const int m0 = blockIdx.x * 128;
    const int n0 = blockIdx.y * 64;
    const int tid = threadIdx.x;
    const int w = tid >> 6, lane = tid & 63;
    const int a = lane & 15, g = lane >> 4;

    __shared__ __align__(16) _Float16 As[128 * 64];
    __shared__ __align__(16) _Float16 Bs[64 * 64];

    f32x4 acc[2][4] = {{{0,0,0,0},{0,0,0,0},{0,0,0,0},{0,0,0,0}},
                       {{0,0,0,0},{0,0,0,0},{0,0,0,0},{0,0,0,0}}};

    for (int step = 0; step < 4; ++step) {
        const int k0 = step * 64;
        // stage A: 4 instrs/wave (128 rows x 128B)
        #pragma unroll
        for (int i = 0; i < 4; ++i) {
            const int f = 4 * w + i;                       // 0..15
            const int rowl = f * 8 + (lane >> 3);          // 0..127
            const int byo = ((lane & 7) * 16) ^ ((rowl & 7) << 4);
            const char* src = (const char*)(A + (size_t)(m0 + rowl) * 256 + k0) + byo;
            __builtin_amdgcn_global_load_lds(
                (const __attribute__((address_space(1))) void*)src,
                (__attribute__((address_space(3))) void*)((char*)As + f * 1024), 16, 0, 0);
        }
        // stage B: 2 instrs/wave
        #pragma unroll
        for (int i = 0; i < 2; ++i) {
            const int f = 2 * w + i;
            const int rowl = f * 8 + (lane >> 3);
            const int byo = ((lane & 7) * 16) ^ ((rowl & 7) << 4);
            const char* src = (const char*)(Wt + (size_t)(n0 + rowl) * 256 + k0) + byo;
            __builtin_amdgcn_global_load_lds(
                (const __attribute__((address_space(1))) void*)src,
                (__attribute__((address_space(3))) void*)((char*)Bs + f * 1024), 16, 0, 0);
        }
        __syncthreads();

        #pragma unroll
        for (int kc = 0; kc < 2; ++kc) {
            half8 af[2], wf[4];
            #pragma unroll
            for (int tt = 0; tt < 2; ++tt) {
                const int row = 32 * w + 16 * tt + a;
                const int byo = (kc * 64 + g * 16) ^ ((row & 7) << 4);
                af[tt] = *(const half8*)((const char*)As + row * 128 + byo);
            }
            #pragma unroll
            for (int nf = 0; nf < 4; ++nf) {
                const int row = 16 * nf + a;
                const int byo = (kc * 64 + g * 16) ^ ((row & 7) << 4);
                wf[nf] = *(const half8*)((const char*)Bs + row * 128 + byo);
            }
            #pragma unroll
            for (int tt = 0; tt < 2; ++tt)
                #pragma unroll
                for (int nf = 0; nf < 4; ++nf)
                    acc[tt][nf] = __builtin_amdgcn_mfma_f32_16x16x32_f16(af[tt], wf[nf], acc[tt][nf], 0,0,0);
        }
        __syncthreads();
    }

    // D[tok = m0+32w+16tt+4g+r][n = n0+16nf+a]
    #pragma unroll
    for (int tt = 0; tt < 2; ++tt) {
        #pragma unroll
        for (int nf = 0; nf < 4; ++nf) {
            const int n = n0 + 16 * nf + a;
            const float bs = bias[n];
            const f32x4 d = acc[tt][nf];
            const int mrow = m0 + 32 * w + 16 * tt + 4 * g;
            #pragma unroll
            for (int r = 0; r < 4; ++r)
                out[(size_t)(mrow + r) * 256 + n] = d[r] + bs;
        }
    }
}

// ---------------------------------------------------------------------------
extern "C" void kernel_launch(void* const* d_in, const int* in_sizes, int n_in,
                              void* d_out, int out_size, void* d_ws, size_t ws_size,
                              hipStream_t stream)
{
    const float* x    = (const float*)d_in[0];
    const int*   mask = (const int*)d_in[1];
    const float* Wq   = (const float*)d_in[2];
    const float* bq   = (const float*)d_in[3];
    const float* Wk   = (const float*)d_in[4];
    const float* bk   = (const float*)d_in[5];
    const float* Wv   = (const float*)d_in[6];
    const float* bv   = (const float*)d_in[7];
    const float* Wo   = (const float*)d_in[8];
    const float* bo   = (const float*)d_in[9];
    float* out = (float*)d_out;

    char* ws = (char*)d_ws;
    size_t off = 0;
    int* bounds = (int*)ws;                 off += 256;
    float* cmv  = (float*)(ws + off);       off += (size_t)BH_ * DK_ * sizeof(float);
    off = (off + 255) & ~(size_t)255;
    float* lw   = (float*)(ws + off);       off += (size_t)2 * BH_ * Nn * sizeof(float);
    const size_t h16_bytes = (size_t)BH_ * Nn * DK_ * sizeof(_Float16);   // 8 MB
    _Float16* Qh  = (_Float16*)(ws + off); off += h16_bytes;
    _Float16* Kh  = (_Float16*)(ws + off); off += h16_bytes;
    _Float16* Vt  = (_Float16*)(ws + off); off += h16_bytes;
    _Float16* Oh  = (_Float16*)(ws + off); off += 2 * h16_bytes;   // 2 splits
    _Float16* ath = (_Float16*)(ws + off); off += h16_bytes;
    _Float16* Wtq = (_Float16*)(ws + off); off += 256 * 256 * sizeof(_Float16);
    _Float16* Wtk = (_Float16*)(ws + off); off += 256 * 256 * sizeof(_Float16);
    _Float16* Wtv = (_Float16*)(ws + off); off += 256 * 256 * sizeof(_Float16);
    _Float16* Wto = (_Float16*)(ws + off); off += 256 * 256 * sizeof(_Float16);

    prep_kernel<<<264, 256, 0, stream>>>(mask, bounds, Wq, Wk, Wv, Wo,
                                         Wtq, Wtk, Wtv, Wto);

    dim3 g1(128, 12);
    qkv_mfma<<<g1, 256, 0, stream>>>(x, Wtq, bq, Wtk, bk, Wtv, bv, Qh, Kh, Vt);

    colmean_kernel<<<BH_, 256, 0, stream>>>(Vt, cmv);

    flash_mfma<<<2048, 256, 0, stream>>>(Qh, Kh, Vt, bounds, Oh, lw);

    dim3 gc(Nn / 64, Bb);
    combine_kernel<<<gc, 256, 0, stream>>>(Oh, lw, bounds, cmv, ath);

    dim3 g3(128, 4);
    proj_mfma<<<g3, 256, 0, stream>>>(ath, Wto, bo, out);
}

// Round 9
// 168.722 us; speedup vs baseline: 1.2381x; 1.0902x over previous
//
#include <hip/hip_runtime.h>
#include <hip/hip_bf16.h>
#include <math.h>

namespace {
constexpr int Bb  = 8;
constexpr int Nn  = 2048;
constexpr int DIN_ = 256;
constexpr int DM_  = 256;
constexpr int NH_  = 4;
constexpr int DK_  = 64;
constexpr int BH_  = Bb * NH_;
constexpr float SCALE = 0.125f;   // 1/sqrt(64)
}

typedef __attribute__((ext_vector_type(8))) _Float16 half8;
typedef __attribute__((ext_vector_type(2))) __fp16 fp16x2;
typedef __attribute__((ext_vector_type(4))) float f32x4;

static __device__ __forceinline__ unsigned pkrtz_u32(float a, float b) {
    union { fp16x2 h; unsigned u; } u;
    u.h = __builtin_amdgcn_cvt_pkrtz(a, b);
    return u.u;
}

static __device__ __forceinline__ half8 h8_from_u32x4(unsigned w0, unsigned w1,
                                                      unsigned w2, unsigned w3) {
    union { unsigned u[4]; half8 h; } u;
    u.u[0] = w0; u.u[1] = w1; u.u[2] = w2; u.u[3] = w3;
    return u.h;
}

// ---------------------------------------------------------------------------
// Kernel 1 (prep): blocks 0-7 bounds + zero cmsum; 8-263 weight transpose.
// ---------------------------------------------------------------------------
__global__ __launch_bounds__(256) void prep_kernel(
    const int* __restrict__ mask, int* __restrict__ bounds,
    float* __restrict__ cmsum,
    const float* __restrict__ W0, const float* __restrict__ W1,
    const float* __restrict__ W2, const float* __restrict__ W3,
    _Float16* __restrict__ T0, _Float16* __restrict__ T1,
    _Float16* __restrict__ T2, _Float16* __restrict__ T3)
{
    const int bid = blockIdx.x;
    const int tid = threadIdx.x;
    if (bid < 8) {
        cmsum[bid * 256 + tid] = 0.0f;      // zero colmean accumulator (8KB)
        const int b = bid;
        __shared__ int smin[256], smax[256];
        int lmin = Nn, lmax = -1;
        for (int i = tid; i < Nn; i += 256) {
            if (mask[b * Nn + i]) {
                if (i < lmin) lmin = i;
                if (i > lmax) lmax = i;
            }
        }
        smin[tid] = lmin; smax[tid] = lmax;
        __syncthreads();
        for (int s = 128; s > 0; s >>= 1) {
            if (tid < s) {
                smin[tid] = min(smin[tid], smin[tid + s]);
                smax[tid] = max(smax[tid], smax[tid + s]);
            }
            __syncthreads();
        }
        if (tid == 0) { bounds[b * 2] = smin[0]; bounds[b * 2 + 1] = smax[0]; }
    } else {
        const int lin = bid - 8;             // 0..255
        const int wsel = lin >> 6;
        const float* W; _Float16* T;
        switch (wsel) {
            case 0: W = W0; T = T0; break;
            case 1: W = W1; T = T1; break;
            case 2: W = W2; T = T2; break;
            default: W = W3; T = T3; break;
        }
        const int idx = (lin & 63) * 256 + tid;
        const int n = idx & 255;
        const int k0 = (idx >> 8) << 2;
        _Float16 h4[4];
        #pragma unroll
        for (int j = 0; j < 4; ++j) h4[j] = (_Float16)W[(size_t)(k0 + j) * 256 + n];
        *(uint2*)&T[(size_t)n * 256 + k0] = *(const uint2*)h4;
    }
}

// ---------------------------------------------------------------------------
// Kernel 2: QKV projection, LDS-staged fp16 MFMA GEMM with fused x-convert
// AND fused colmean (z=2): per-wave column partial + atomicAdd into cmsum.
// grid (128, 12): m0 = bx*128, zsel = by>>2 (Q/K/V), n0 = (by&3)*64.
// ---------------------------------------------------------------------------
__global__ __launch_bounds__(256) void qkv_mfma(
    const float* __restrict__ x,
    const _Float16* __restrict__ Wtq, const float* __restrict__ bq,
    const _Float16* __restrict__ Wtk, const float* __restrict__ bk,
    const _Float16* __restrict__ Wtv, const float* __restrict__ bv,
    _Float16* __restrict__ Qh, _Float16* __restrict__ Kh, _Float16* __restrict__ Vt,
    float* __restrict__ cmsum)
{
    const int zsel = blockIdx.y >> 2;
    const int n0 = (blockIdx.y & 3) * 64;
    const int m0 = blockIdx.x * 128;
    const _Float16* Wt; const float* bias;
    if (zsel == 0)      { Wt = Wtq; bias = bq; }
    else if (zsel == 1) { Wt = Wtk; bias = bk; }
    else                { Wt = Wtv; bias = bv; }

    const int tid = threadIdx.x;
    const int w = tid >> 6, lane = tid & 63;
    const int a = lane & 15, g = lane >> 4;
    const int b = m0 >> 11;                  // 128-row tile never crosses batch

    __shared__ __align__(16) _Float16 As[128 * 64];   // 16KB, swizzled rows of 128B
    __shared__ __align__(16) _Float16 Bs[64 * 64];    // 8KB

    f32x4 acc[4][2] = {{{0,0,0,0},{0,0,0,0}},{{0,0,0,0},{0,0,0,0}},
                       {{0,0,0,0},{0,0,0,0}},{{0,0,0,0},{0,0,0,0}}};

    for (int step = 0; step < 4; ++step) {
        const int k0 = step * 64;
        // ---- stage A: convert x fp32->fp16 (RTE), swizzled ds_write ----
        {
            const int rb = tid >> 3, fc = tid & 7;
            #pragma unroll
            for (int p = 0; p < 4; ++p) {
                const int row = p * 32 + rb;
                const float4 v0 = *(const float4*)&x[(size_t)(m0 + row) * 256 + k0 + fc * 8];
                const float4 v1 = *(const float4*)&x[(size_t)(m0 + row) * 256 + k0 + fc * 8 + 4];
                _Float16 h[8];
                h[0]=(_Float16)v0.x; h[1]=(_Float16)v0.y; h[2]=(_Float16)v0.z; h[3]=(_Float16)v0.w;
                h[4]=(_Float16)v1.x; h[5]=(_Float16)v1.y; h[6]=(_Float16)v1.z; h[7]=(_Float16)v1.w;
                const int byo = (fc * 16) ^ ((row & 7) << 4);
                *(uint4*)((char*)As + row * 128 + byo) = *(const uint4*)h;
            }
        }
        // ---- stage B: global_load_lds, pre-swizzled source, linear dest ----
        #pragma unroll
        for (int i = 0; i < 2; ++i) {
            const int f = 2 * w + i;                       // 0..7
            const int rowl = f * 8 + (lane >> 3);          // 0..63
            const int byo = ((lane & 7) * 16) ^ ((rowl & 7) << 4);
            const char* src = (const char*)(Wt + (size_t)(n0 + rowl) * 256 + k0) + byo;
            __builtin_amdgcn_global_load_lds(
                (const __attribute__((address_space(1))) void*)src,
                (__attribute__((address_space(3))) void*)((char*)Bs + f * 1024), 16, 0, 0);
        }
        __syncthreads();

        // ---- compute: 2 k-chunks of 32 ----
        #pragma unroll
        for (int kc = 0; kc < 2; ++kc) {
            half8 xf[2], wf[4];
            #pragma unroll
            for (int tt = 0; tt < 2; ++tt) {
                const int row = 32 * w + 16 * tt + a;
                const int byo = (kc * 64 + g * 16) ^ ((row & 7) << 4);
                xf[tt] = *(const half8*)((const char*)As + row * 128 + byo);
            }
            #pragma unroll
            for (int nf = 0; nf < 4; ++nf) {
                const int row = 16 * nf + a;
                const int byo = (kc * 64 + g * 16) ^ ((row & 7) << 4);
                wf[nf] = *(const half8*)((const char*)Bs + row * 128 + byo);
            }
            if (zsel < 2) {
                #pragma unroll
                for (int nf = 0; nf < 4; ++nf)
                    #pragma unroll
                    for (int tt = 0; tt < 2; ++tt)
                        acc[nf][tt] = __builtin_amdgcn_mfma_f32_16x16x32_f16(wf[nf], xf[tt], acc[nf][tt], 0,0,0);
            } else {
                #pragma unroll
                for (int nf = 0; nf < 4; ++nf)
                    #pragma unroll
                    for (int tt = 0; tt < 2; ++tt)
                        acc[nf][tt] = __builtin_amdgcn_mfma_f32_16x16x32_f16(xf[tt], wf[nf], acc[nf][tt], 0,0,0);
            }
        }
        __syncthreads();
    }

    // ---- stores ----
    if (zsel < 2) {
        // D[n = n0+16nf+4g+r][tok = m0+32w+16tt+a]
        _Float16* out = zsel ? Kh : Qh;
        #pragma unroll
        for (int nf = 0; nf < 4; ++nf) {
            const int nb = n0 + 16 * nf + 4 * g;
            const f32x4 bi = *(const f32x4*)&bias[nb];
            const int h = nb >> 6, dkb = nb & 63;
            #pragma unroll
            for (int tt = 0; tt < 2; ++tt) {
                const int tok = (m0 + 32 * w + 16 * tt + a) & 2047;
                const f32x4 d = acc[nf][tt];
                _Float16 q4[4];
                q4[0] = (_Float16)(d[0] + bi[0]);
                q4[1] = (_Float16)(d[1] + bi[1]);
                q4[2] = (_Float16)(d[2] + bi[2]);
                q4[3] = (_Float16)(d[3] + bi[3]);
                *(uint2*)&out[(((size_t)(b * NH_ + h)) * Nn + tok) * DK_ + dkb] = *(const uint2*)q4;
            }
        }
    } else {
        // D[tok = m0+32w+16tt+4g+r][n = n0+16nf+a]
        const int h = n0 >> 6;
        #pragma unroll
        for (int nf = 0; nf < 4; ++nf) {
            const int n = n0 + 16 * nf + a;
            const float bs = bias[n];
            const int dk = 16 * nf + a;
            float csum = 8.0f * bs;                       // 8 rows per lane
            #pragma unroll
            for (int tt = 0; tt < 2; ++tt) {
                const int tokb = (m0 + 32 * w + 16 * tt + 4 * g) & 2047;
                const f32x4 d = acc[nf][tt];
                csum += d[0] + d[1] + d[2] + d[3];
                uint2 pk;
                pk.x = pkrtz_u32(d[0] + bs, d[1] + bs);
                pk.y = pkrtz_u32(d[2] + bs, d[3] + bs);
                *(uint2*)&Vt[(((size_t)(b * NH_ + h)) * DK_ + dk) * Nn + tokb] = pk;
            }
            // fused colmean partial: sum over this wave's 32 rows (reduce g)
            csum += __shfl_xor(csum, 16, 64);
            csum += __shfl_xor(csum, 32, 64);
            if (g == 0)
                atomicAdd(&cmsum[(b * NH_ + h) * DK_ + dk], csum);
        }
    }
}

// ---------------------------------------------------------------------------
// Kernel 3: flash attention (R8 structure, bit-identical output).
// ---------------------------------------------------------------------------
__global__ __launch_bounds__(256) void flash_mfma(
    const _Float16* __restrict__ Q, const _Float16* __restrict__ K,
    const _Float16* __restrict__ Vt, const int* __restrict__ bounds,
    _Float16* __restrict__ Oh, float* __restrict__ lw)
{
    const int bid = blockIdx.x;
    const int xcd = bid & 7;
    const int rest = bid >> 3;
    const int qb  = rest & 31;
    const int j   = (rest >> 5) & 3;
    const int s   = rest >> 7;
    const int bh  = j * 8 + xcd;
    const int b  = bh >> 2, h = bh & 3;
    const int q0 = qb * 64;
    const int tid  = threadIdx.x;
    const int w    = tid >> 6;
    const int lane = tid & 63;
    const int a = lane & 15, g = lane >> 4;
    const int start = bounds[2 * b], endv = bounds[2 * b + 1];

    if (q0 + 63 < start || q0 >= endv) return;

    __shared__ __align__(16) _Float16 kfr[2][8][512];
    __shared__ __align__(16) _Float16 vfr[2][8][512];

    const _Float16* Qb = Q  + (size_t)bh * Nn * DK_;
    const _Float16* Kb = K  + (size_t)bh * Nn * DK_;
    const _Float16* Vb = Vt + (size_t)bh * DK_ * Nn;

    const int qrow = q0 + 16 * w + a;
    const half8 qf0 = *(const half8*)&Qb[(size_t)qrow * DK_ + 8 * g];
    const half8 qf1 = *(const half8*)&Qb[(size_t)qrow * DK_ + 32 + 8 * g];

    float l_i = 0.0f;
    f32x4 o0 = {0.f,0.f,0.f,0.f}, o1 = {0.f,0.f,0.f,0.f};
    f32x4 o2 = {0.f,0.f,0.f,0.f}, o3 = {0.f,0.f,0.f,0.f};

#define STAGE(cbuf, kt_) do {                                                        \
        _Pragma("unroll")                                                            \
        for (int ff = 0; ff < 2; ++ff) {                                             \
            const int f  = 2 * w + ff;                                               \
            const int tt = f >> 1, cc = f & 1;                                       \
            const _Float16* ks = &Kb[(size_t)((kt_) + 16 * tt + a) * DK_ + 32 * cc + 8 * g]; \
            __builtin_amdgcn_global_load_lds(                                        \
                (const __attribute__((address_space(1))) void*)ks,                   \
                (__attribute__((address_space(3))) void*)&kfr[cbuf][f][0], 16, 0, 0);\
            const _Float16* vs = &Vb[(size_t)(16 * tt + a) * Nn + (kt_) + 32 * cc + 8 * g]; \
            __builtin_amdgcn_global_load_lds(                                        \
                (const __attribute__((address_space(1))) void*)vs,                   \
                (__attribute__((address_space(3))) void*)&vfr[cbuf][f][0], 16, 0, 0);\
        }                                                                            \
    } while (0)

    const int t0 = start >> 6, t1 = (endv + 63) >> 6;
    const int nt = t1 - t0;
    const int n0t = (nt + 1) >> 1;
    const int ts = (s == 0) ? t0 : t0 + n0t;
    const int te = (s == 0) ? t0 + n0t : t1;

    if (ts < te) {
        const int lo = ts * 64, hiend = te * 64;
        int c = 0;
        STAGE(0, lo);

        for (int kt = lo; kt < hiend; kt += 64) {
            const int nxt = kt + 64;
            if (nxt < hiend) {
                STAGE(c ^ 1, nxt);
                asm volatile("s_waitcnt vmcnt(4)" ::: "memory");
            } else {
                asm volatile("s_waitcnt vmcnt(0)" ::: "memory");
            }
            __builtin_amdgcn_s_barrier();

            const _Float16* kf = &kfr[c][0][0];
            const _Float16* vf = &vfr[c][0][0];

            f32x4 st0 = {0.f,0.f,0.f,0.f}, st1 = {0.f,0.f,0.f,0.f};
            f32x4 st2 = {0.f,0.f,0.f,0.f}, st3 = {0.f,0.f,0.f,0.f};
            __builtin_amdgcn_s_setprio(1);
            st0 = __builtin_amdgcn_mfma_f32_16x16x32_f16(*(const half8*)&kf[0*512 + lane*8], qf0, st0, 0,0,0);
            st0 = __builtin_amdgcn_mfma_f32_16x16x32_f16(*(const half8*)&kf[1*512 + lane*8], qf1, st0, 0,0,0);
            st1 = __builtin_amdgcn_mfma_f32_16x16x32_f16(*(const half8*)&kf[2*512 + lane*8], qf0, st1, 0,0,0);
            st1 = __builtin_amdgcn_mfma_f32_16x16x32_f16(*(const half8*)&kf[3*512 + lane*8], qf1, st1, 0,0,0);
            st2 = __builtin_amdgcn_mfma_f32_16x16x32_f16(*(const half8*)&kf[4*512 + lane*8], qf0, st2, 0,0,0);
            st2 = __builtin_amdgcn_mfma_f32_16x16x32_f16(*(const half8*)&kf[5*512 + lane*8], qf1, st2, 0,0,0);
            st3 = __builtin_amdgcn_mfma_f32_16x16x32_f16(*(const half8*)&kf[6*512 + lane*8], qf0, st3, 0,0,0);
            st3 = __builtin_amdgcn_mfma_f32_16x16x32_f16(*(const half8*)&kf[7*512 + lane*8], qf1, st3, 0,0,0);
            __builtin_amdgcn_s_setprio(0);

            float pv[4][4];
            float rsum = 0.0f;
            const bool edge = (kt < start) || (kt + 64 > endv);
            if (edge) {
                #pragma unroll
                for (int t = 0; t < 4; ++t) {
                    const f32x4 sv = (t == 0) ? st0 : (t == 1) ? st1 : (t == 2) ? st2 : st3;
                    #pragma unroll
                    for (int r = 0; r < 4; ++r) {
                        const int col = kt + 16 * t + 4 * g + r;
                        const bool ok = (col >= start) && (col < endv);
                        const float e = ok ? __expf(sv[r] * SCALE) : 0.0f;
                        pv[t][r] = e;
                        rsum += e;
                    }
                }
            } else {
                #pragma unroll
                for (int t = 0; t < 4; ++t) {
                    const f32x4 sv = (t == 0) ? st0 : (t == 1) ? st1 : (t == 2) ? st2 : st3;
                    #pragma unroll
                    for (int r = 0; r < 4; ++r) {
                        const float e = __expf(sv[r] * SCALE);
                        pv[t][r] = e;
                        rsum += e;
                    }
                }
            }
            rsum += __shfl_xor(rsum, 16, 64);
            rsum += __shfl_xor(rsum, 32, 64);
            l_i += rsum;

            unsigned pk[4][2];
            #pragma unroll
            for (int t = 0; t < 4; ++t) {
                pk[t][0] = pkrtz_u32(pv[t][0], pv[t][1]);
                pk[t][1] = pkrtz_u32(pv[t][2], pv[t][3]);
            }
            const int gsel = g >> 1;
            unsigned aw[2][4];
            #pragma unroll
            for (int cq = 0; cq < 2; ++cq) {
                #pragma unroll
                for (int wd = 0; wd < 4; ++wd) {
                    const int srcLane = a + 16 * (2 * (g & 1) + (wd >> 1));
                    const int lo2 = __shfl((int)pk[2 * cq    ][wd & 1], srcLane, 64);
                    const int hi2 = __shfl((int)pk[2 * cq + 1][wd & 1], srcLane, 64);
                    aw[cq][wd] = (unsigned)(gsel ? hi2 : lo2);
                }
            }
            const half8 pa0 = h8_from_u32x4(aw[0][0], aw[0][1], aw[0][2], aw[0][3]);
            const half8 pa1 = h8_from_u32x4(aw[1][0], aw[1][1], aw[1][2], aw[1][3]);

            __builtin_amdgcn_s_setprio(1);
            o0 = __builtin_amdgcn_mfma_f32_16x16x32_f16(pa0, *(const half8*)&vf[0*512 + lane*8], o0, 0,0,0);
            o0 = __builtin_amdgcn_mfma_f32_16x16x32_f16(pa1, *(const half8*)&vf[1*512 + lane*8], o0, 0,0,0);
            o1 = __builtin_amdgcn_mfma_f32_16x16x32_f16(pa0, *(const half8*)&vf[2*512 + lane*8], o1, 0,0,0);
            o1 = __builtin_amdgcn_mfma_f32_16x16x32_f16(pa1, *(const half8*)&vf[3*512 + lane*8], o1, 0,0,0);
            o2 = __builtin_amdgcn_mfma_f32_16x16x32_f16(pa0, *(const half8*)&vf[4*512 + lane*8], o2, 0,0,0);
            o2 = __builtin_amdgcn_mfma_f32_16x16x32_f16(pa1, *(const half8*)&vf[5*512 + lane*8], o2, 0,0,0);
            o3 = __builtin_amdgcn_mfma_f32_16x16x32_f16(pa0, *(const half8*)&vf[6*512 + lane*8], o3, 0,0,0);
            o3 = __builtin_amdgcn_mfma_f32_16x16x32_f16(pa1, *(const half8*)&vf[7*512 + lane*8], o3, 0,0,0);
            __builtin_amdgcn_s_setprio(0);

            asm volatile("" ::: "memory");
            __builtin_amdgcn_s_barrier();
            c ^= 1;
        }
    }
#undef STAGE

    const size_t half = (size_t)Bb * Nn * DM_;
    _Float16* ob = Oh + (size_t)s * half + ((size_t)b * Nn) * DM_ + h * DK_;
    #pragma unroll
    for (int td = 0; td < 4; ++td) {
        const f32x4 ov = (td == 0) ? o0 : (td == 1) ? o1 : (td == 2) ? o2 : o3;
        #pragma unroll
        for (int r = 0; r < 4; ++r) {
            const int qr = q0 + 16 * w + 4 * g + r;
            ob[(size_t)qr * DM_ + 16 * td + a] = (_Float16)ov[r];
        }
    }
    if (g == 0) {
        const int tok = q0 + 16 * w + a;
        lw[(size_t)s * BH_ * Nn + (size_t)bh * Nn + tok] = l_i;
    }
}

// ---------------------------------------------------------------------------
// Kernel 4: output projection with FUSED split-combine.
// A-tile = (O0+O1)*inv (valid rows) or colmean (invalid), built in registers
// during staging -> swizzled ds_write.  head h == k-step (DK=64 == BK).
// grid (128, 4).
// ---------------------------------------------------------------------------
__global__ __launch_bounds__(256) void proj_mfma(
    const _Float16* __restrict__ Oh, const float* __restrict__ lw,
    const int* __restrict__ bounds, const float* __restrict__ cmsum,
    const _Float16* __restrict__ Wt, const float* __restrict__ bias,
    float* __restrict__ out)
{
    const int m0 = blockIdx.x * 128;
    const int n0 = blockIdx.y * 64;
    const int tid = threadIdx.x;
    const int w = tid >> 6, lane = tid & 63;
    const int a = lane & 15, g = lane >> 4;
    const int b = m0 >> 11;
    const int start = bounds[2 * b], endv = bounds[2 * b + 1];

    __shared__ __align__(16) _Float16 As[128 * 64];
    __shared__ __align__(16) _Float16 Bs[64 * 64];

    const size_t half = (size_t)Bb * Nn * DM_;

    f32x4 acc[2][4] = {{{0,0,0,0},{0,0,0,0},{0,0,0,0},{0,0,0,0}},
                       {{0,0,0,0},{0,0,0,0},{0,0,0,0},{0,0,0,0}}};

    for (int step = 0; step < 4; ++step) {
        const int k0 = step * 64;            // head h == step
        // ---- stage A: combine splits in registers, swizzled ds_write ----
        {
            const int rb = tid >> 3, fc = tid & 7;
            #pragma unroll
            for (int p = 0; p < 4; ++p) {
                const int row = p * 32 + rb;
                const int tok = (m0 + row) & 2047;
                const bool valid = (tok >= start) && (tok < endv);
                const size_t rowoff = ((size_t)b * Nn + tok) * DM_ + k0 + fc * 8;
                _Float16 h[8];
                if (valid) {
                    const int bh = b * NH_ + step;
                    const float l0 = lw[(size_t)bh * Nn + tok];
                    const float l1 = lw[(size_t)BH_ * Nn + (size_t)bh * Nn + tok];
                    const float inv = 1.0f / (l0 + l1);
                    half8 a0 = *(const half8*)&Oh[rowoff];
                    half8 a1 = *(const half8*)&Oh[half + rowoff];
                    #pragma unroll
                    for (int k = 0; k < 8; ++k)
                        h[k] = (_Float16)(((float)a0[k] + (float)a1[k]) * inv);
                } else {
                    const float* cmp = &cmsum[(b * NH_ + step) * DK_ + fc * 8];
                    const float4 c0 = *(const float4*)cmp;
                    const float4 c1 = *(const float4*)(cmp + 4);
                    h[0]=(_Float16)(c0.x*(1.0f/2048.0f)); h[1]=(_Float16)(c0.y*(1.0f/2048.0f));
                    h[2]=(_Float16)(c0.z*(1.0f/2048.0f)); h[3]=(_Float16)(c0.w*(1.0f/2048.0f));
                    h[4]=(_Float16)(c1.x*(1.0f/2048.0f)); h[5]=(_Float16)(c1.y*(1.0f/2048.0f));
                    h[6]=(_Float16)(c1.z*(1.0f/2048.0f)); h[7]=(_Float16)(c1.w*(1.0f/2048.0f));
                }
                const int byo = (fc * 16) ^ ((row & 7) << 4);
                *(uint4*)((char*)As + row * 128 + byo) = *(const uint4*)h;
            }
        }
        // ---- stage B: global_load_lds, pre-swizzled source ----
        #pragma unroll
        for (int i = 0; i < 2; ++i) {
            const int f = 2 * w + i;
            const int rowl = f * 8 + (lane >> 3);
            const int byo = ((lane & 7) * 16) ^ ((rowl & 7) << 4);
            const char* src = (const char*)(Wt + (size_t)(n0 + rowl) * 256 + k0) + byo;
            __builtin_amdgcn_global_load_lds(
                (const __attribute__((address_space(1))) void*)src,
                (__attribute__((address_space(3))) void*)((char*)Bs + f * 1024), 16, 0, 0);
        }
        __syncthreads();

        #pragma unroll
        for (int kc = 0; kc < 2; ++kc) {
            half8 af[2], wf[4];
            #pragma unroll
            for (int tt = 0; tt < 2; ++tt) {
                const int row = 32 * w + 16 * tt + a;
                const int byo = (kc * 64 + g * 16) ^ ((row & 7) << 4);
                af[tt] = *(const half8*)((const char*)As + row * 128 + byo);
            }
            #pragma unroll
            for (int nf = 0; nf < 4; ++nf) {
                const int row = 16 * nf + a;
                const int byo = (kc * 64 + g * 16) ^ ((row & 7) << 4);
                wf[nf] = *(const half8*)((const char*)Bs + row * 128 + byo);
            }
            #pragma unroll
            for (int tt = 0; tt < 2; ++tt)
                #pragma unroll
                for (int nf = 0; nf < 4; ++nf)
                    acc[tt][nf] = __builtin_amdgcn_mfma_f32_16x16x32_f16(af[tt], wf[nf], acc[tt][nf], 0,0,0);
        }
        __syncthreads();
    }

    // D[tok = m0+32w+16tt+4g+r][n = n0+16nf+a]
    #pragma unroll
    for (int tt = 0; tt < 2; ++tt) {
        #pragma unroll
        for (int nf = 0; nf < 4; ++nf) {
            const int n = n0 + 16 * nf + a;
            const float bs = bias[n];
            const f32x4 d = acc[tt][nf];
            const int mrow = m0 + 32 * w + 16 * tt + 4 * g;
            #pragma unroll
            for (int r = 0; r < 4; ++r)
                out[(size_t)(mrow + r) * 256 + n] = d[r] + bs;
        }
    }
}

// ---------------------------------------------------------------------------
extern "C" void kernel_launch(void* const* d_in, const int* in_sizes, int n_in,
                              void* d_out, int out_size, void* d_ws, size_t ws_size,
                              hipStream_t stream)
{
    const float* x    = (const float*)d_in[0];
    const int*   mask = (const int*)d_in[1];
    const float* Wq   = (const float*)d_in[2];
    const float* bq   = (const float*)d_in[3];
    const float* Wk   = (const float*)d_in[4];
    const float* bk   = (const float*)d_in[5];
    const float* Wv   = (const float*)d_in[6];
    const float* bv   = (const float*)d_in[7];
    const float* Wo   = (const float*)d_in[8];
    const float* bo   = (const float*)d_in[9];
    float* out = (float*)d_out;

    char* ws = (char*)d_ws;
    size_t off = 0;
    int* bounds = (int*)ws;                 off += 256;
    float* cmsum = (float*)(ws + off);      off += (size_t)BH_ * DK_ * sizeof(float);
    off = (off + 255) & ~(size_t)255;
    float* lw   = (float*)(ws + off);       off += (size_t)2 * BH_ * Nn * sizeof(float);
    const size_t h16_bytes = (size_t)BH_ * Nn * DK_ * sizeof(_Float16);   // 8 MB
    _Float16* Qh  = (_Float16*)(ws + off); off += h16_bytes;
    _Float16* Kh  = (_Float16*)(ws + off); off += h16_bytes;
    _Float16* Vt  = (_Float16*)(ws + off); off += h16_bytes;
    _Float16* Oh  = (_Float16*)(ws + off); off += 2 * h16_bytes;   // 2 splits
    _Float16* Wtq = (_Float16*)(ws + off); off += 256 * 256 * sizeof(_Float16);
    _Float16* Wtk = (_Float16*)(ws + off); off += 256 * 256 * sizeof(_Float16);
    _Float16* Wtv = (_Float16*)(ws + off); off += 256 * 256 * sizeof(_Float16);
    _Float16* Wto = (_Float16*)(ws + off); off += 256 * 256 * sizeof(_Float16);

    prep_kernel<<<264, 256, 0, stream>>>(mask, bounds, cmsum, Wq, Wk, Wv, Wo,
                                         Wtq, Wtk, Wtv, Wto);

    dim3 g1(128, 12);
    qkv_mfma<<<g1, 256, 0, stream>>>(x, Wtq, bq, Wtk, bk, Wtv, bv,
                                     Qh, Kh, Vt, cmsum);

    flash_mfma<<<2048, 256, 0, stream>>>(Qh, Kh, Vt, bounds, Oh, lw);

    dim3 g3(128, 4);
    proj_mfma<<<g3, 256, 0, stream>>>(Oh, lw, bounds, cmsum, Wto, bo, out);
}